// Round 9
// baseline (266.102 us; speedup 1.0000x reference)
//
#include <hip/hip_runtime.h>
#include <math.h>

// ---------------- workspace layout (bytes) ----------------
#define X_B      0         // 512*1024 f32   = 2,097,152
#define BBOX_B   2097152   // 36*1024 f32    = 147,456
#define PROPS_B  2244608   // 9216 float4    = 147,456
#define KEYS_B   2392064   // 9216 u64       = 73,728
#define RANK_B   2465792   // 9216 u32       = 36,864
#define SKEYS_B  2502656   // 9216 u64       = 73,728
#define SBOX_B   2576384   // 9216 float4    = 147,456
#define MASK_B   2725888   // 9216*144 u64   = 10,616,832 (end 13,342,720)
#define WS_NEED  13400000

typedef unsigned long long u64;
typedef double v4d __attribute__((ext_vector_type(4)));

// ================= conv 3x3 (256->512, 32x32, pad 1) + ReLU =================
// R9: software-pipelined half-chunks (32 ci). Per h: issue global loads for
// h+1 into REGISTERS, compute h from LDS buf[h&1], write regs to buf[h&1^1],
// one sync. Global latency (~600-900cy) hides under the ~4600cy MFMA phase.
// LDS 2x(16co x 292 + 32ci x 137) = 72.7 KB -> still 2 blocks/CU.
// Compute mapping unchanged (ci = 4u+q, u<8): A[i=n][k=q]=W[co0+n][ci],
// B[k=q][j=n]=feat[ci][px xn]; D row = q+4*reg (probe-verified), col = n.
// Invalid feature rows (block-constant) are never written -> stay zero from
// the one-time init, across all h and both buffers.
__global__ __launch_bounds__(256, 2) void conv3x3_mfma_k(
    const float* __restrict__ feat, const float* __restrict__ w,
    const float* __restrict__ bias, float* __restrict__ xout)
{
  __shared__ float wl2[2][4672];   // [buf][co*292 + ci5*9 + tap]  37,376 B
  __shared__ float fl2[2][4416];   // [buf][ci*137 + row*34 +1 +x] 35,328 B

  const int tid = threadIdx.x;
  const int bid = blockIdx.x;
  const int ct = ((bid & 7) << 2) | ((bid >> 3) >> 4);   // co-tile 0..31
  const int g  = (bid >> 3) & 15;                        // px-group 0..15
  const int co0 = ct << 4;
  const int y0  = g << 1;

  const int lane = tid & 63, wv = tid >> 6;
  const int q = lane >> 4, n = lane & 15;
  const int wy = wv >> 1, xb = (wv & 1) << 4;
  const int xn = xb + n;

  // staging indices (constant over h)
  int wco[5], ws4[5]; bool wok[5];
  #pragma unroll
  for (int i = 0; i < 5; ++i) {
    const int idx4 = tid + (i << 8);          // 0..1279; 1152 valid
    wok[i] = idx4 < 1152;
    const int co = idx4 / 72;                 // 72 float4 per co (288 floats)
    wco[i] = co; ws4[i] = idx4 - co * 72;
  }
  int fci[4], frr[4], fx4[4]; bool fok[4];
  #pragma unroll
  for (int i = 0; i < 4; ++i) {
    const int idx4 = tid + (i << 8);          // 0..1023
    fci[i] = idx4 >> 5; frr[i] = (idx4 >> 3) & 3; fx4[i] = idx4 & 7;
    fok[i] = ((unsigned)(y0 - 1 + frr[i]) < 32u);
  }

  // zero feature buffers once: pad cols + invalid rows stay 0 for all h
  for (int i = tid; i < 2 * 4416; i += 256) ((float*)fl2)[i] = 0.0f;

  const float4* feat4 = (const float4*)feat;
  float4 wr[5], fr[4];

  // prologue: load h=0 into regs
  #pragma unroll
  for (int i = 0; i < 5; ++i)
    if (wok[i])
      wr[i] = *(const float4*)(w + (co0 + wco[i]) * 2304 + (ws4[i] << 2));
  #pragma unroll
  for (int i = 0; i < 4; ++i)
    if (fok[i])
      fr[i] = feat4[(fci[i] << 8) + ((y0 - 1 + frr[i]) << 3) + fx4[i]];
  __syncthreads();                            // zero-init complete
  #pragma unroll
  for (int i = 0; i < 5; ++i)
    if (wok[i]) *(float4*)&wl2[0][wco[i] * 292 + (ws4[i] << 2)] = wr[i];
  #pragma unroll
  for (int i = 0; i < 4; ++i)
    if (fok[i])
      *(float4*)&fl2[0][fci[i] * 137 + frr[i] * 34 + 1 + (fx4[i] << 2)] = fr[i];
  __syncthreads();

  v4d ac0 = {0.0, 0.0, 0.0, 0.0}, ac1 = {0.0, 0.0, 0.0, 0.0};
  v4d ac2 = {0.0, 0.0, 0.0, 0.0}, ac3 = {0.0, 0.0, 0.0, 0.0};

  for (int h = 0; h < 8; ++h) {               // 8 half-chunks of 32 ci
    const int b = h & 1;
    if (h < 7) {                              // issue loads for h+1
      const int cb = (h + 1) << 5;
      #pragma unroll
      for (int i = 0; i < 5; ++i)
        if (wok[i])
          wr[i] = *(const float4*)(w + (co0 + wco[i]) * 2304 +
                                   (h + 1) * 288 + (ws4[i] << 2));
      #pragma unroll
      for (int i = 0; i < 4; ++i)
        if (fok[i])
          fr[i] = feat4[((cb + fci[i]) << 8) + ((y0 - 1 + frr[i]) << 3) + fx4[i]];
    }
    // compute h from buf b: 9 taps x 8 mfma (K=32), 4 indep chains
    #pragma unroll
    for (int tap = 0; tap < 9; ++tap) {
      const int ky = tap / 3, kx = tap - 3 * (tap / 3);
      const float* ab = &wl2[b][n * 292 + q * 9 + tap];               // +u*36
      const float* bb = &fl2[b][q * 137 + (wy + ky) * 34 + xn + kx];  // +u*548
      #pragma unroll
      for (int u = 0; u < 8; u += 4) {
        ac0 = __builtin_amdgcn_mfma_f64_16x16x4f64(
            (double)ab[(u + 0) * 36], (double)bb[(u + 0) * 548], ac0, 0, 0, 0);
        ac1 = __builtin_amdgcn_mfma_f64_16x16x4f64(
            (double)ab[(u + 1) * 36], (double)bb[(u + 1) * 548], ac1, 0, 0, 0);
        ac2 = __builtin_amdgcn_mfma_f64_16x16x4f64(
            (double)ab[(u + 2) * 36], (double)bb[(u + 2) * 548], ac2, 0, 0, 0);
        ac3 = __builtin_amdgcn_mfma_f64_16x16x4f64(
            (double)ab[(u + 3) * 36], (double)bb[(u + 3) * 548], ac3, 0, 0, 0);
      }
    }
    if (h < 7) {                              // write h+1 into other buffer
      const int b2 = b ^ 1;
      #pragma unroll
      for (int i = 0; i < 5; ++i)
        if (wok[i]) *(float4*)&wl2[b2][wco[i] * 292 + (ws4[i] << 2)] = wr[i];
      #pragma unroll
      for (int i = 0; i < 4; ++i)
        if (fok[i])
          *(float4*)&fl2[b2][fci[i] * 137 + frr[i] * 34 + 1 + (fx4[i] << 2)] = fr[i];
    }
    __syncthreads();
  }

  // epilogue: D[m][n] with m = q + 4*i (probe-verified), n = px col
  const int pbase = (g << 6) + (wv << 4) + n;
  #pragma unroll
  for (int i = 0; i < 4; ++i) {
    const int co = co0 + q + (i << 2);
    const double s = (ac0[i] + ac1[i]) + (ac2[i] + ac3[i]);
    const double v = fmax(s + (double)bias[co], 0.0);
    xout[(co << 10) + pbase] = (float)v;
  }
}

// ========== fallback conv (small ws) ========================================
#define CPITCH 38
#define CCHS   (18 * CPITCH)
__global__ __launch_bounds__(256) void conv3x3_relu_fb_k(
    const float* __restrict__ feat, const float* __restrict__ w,
    const float* __restrict__ bias, float* __restrict__ xout)
{
  __shared__ float il[2][8 * CCHS];
  const int cp = blockIdx.x >> 1, h = blockIdx.x & 1;
  const int tid = threadIdx.x;
  const int h16 = h << 4;
  const int co0 = cp << 1;
  for (int i = tid; i < 8 * CCHS; i += 256) { il[0][i] = 0.0f; il[1][i] = 0.0f; }
  const int yl = tid >> 4;
  const int x0 = (tid & 15) << 1;
  double aA0 = 0.0, aA1 = 0.0, aB0 = 0.0, aB1 = 0.0;
  const float4* feat4 = (const float4*)feat;
  float4 pf[5]; int pch[5], pt[5], pc4[5], pok[5];
  #pragma unroll
  for (int k = 0; k < 5; ++k) {
    const int i = tid + (k << 8);
    const int ch = i / 144, rem = i - ch * 144;
    const int t = rem >> 3, c4 = rem & 7;
    const int g = h16 - 1 + t;
    pch[k] = ch; pt[k] = t; pc4[k] = c4;
    pok[k] = (i < 1152) && ((unsigned)g < 32u);
    pf[k] = pok[k] ? feat4[(ch << 8) + (g << 3) + c4] : float4{0.f,0.f,0.f,0.f};
  }
  __syncthreads();
  for (int cc = 0; cc < 256; cc += 8) {
    const int buf = (cc >> 3) & 1;
    #pragma unroll
    for (int k = 0; k < 5; ++k)
      if (pok[k]) {
        float* p = &il[buf][pch[k] * CCHS + pt[k] * CPITCH + (pc4[k] << 2) + 1];
        p[0] = pf[k].x; p[1] = pf[k].y; p[2] = pf[k].z; p[3] = pf[k].w;
      }
    if (cc + 8 < 256) {
      #pragma unroll
      for (int k = 0; k < 5; ++k) {
        const int g = h16 - 1 + pt[k];
        if (pok[k]) pf[k] = feat4[((cc + 8 + pch[k]) << 8) + (g << 3) + pc4[k]];
      }
    }
    __syncthreads();
    #pragma unroll
    for (int cl = 0; cl < 8; ++cl) {
      const float* wAp = w + co0 * 2304 + (cc + cl) * 9;
      const float* wBp = wAp + 2304;
      double wa[9], wb[9];
      #pragma unroll
      for (int q = 0; q < 9; ++q) { wa[q] = (double)wAp[q]; wb[q] = (double)wBp[q]; }
      const float* ir = &il[buf][cl * CCHS + yl * CPITCH + x0];
      #pragma unroll
      for (int ky = 0; ky < 3; ++ky) {
        const float2 q0 = *(const float2*)(ir + ky * CPITCH);
        const float2 q1 = *(const float2*)(ir + ky * CPITCH + 2);
        const double v0 = (double)q0.x, v1 = (double)q0.y;
        const double v2 = (double)q1.x, v3 = (double)q1.y;
        aA0 += v0 * wa[3*ky+0] + v1 * wa[3*ky+1] + v2 * wa[3*ky+2];
        aA1 += v1 * wa[3*ky+0] + v2 * wa[3*ky+1] + v3 * wa[3*ky+2];
        aB0 += v0 * wb[3*ky+0] + v1 * wb[3*ky+1] + v2 * wb[3*ky+2];
        aB1 += v1 * wb[3*ky+0] + v2 * wb[3*ky+1] + v3 * wb[3*ky+2];
      }
    }
  }
  const double bA = (double)bias[co0], bB = (double)bias[co0 + 1];
  const int y = h16 + yl;
  float2 rA, rB;
  rA.x = (float)fmax(aA0 + bA, 0.0); rA.y = (float)fmax(aA1 + bA, 0.0);
  rB.x = (float)fmax(aB0 + bB, 0.0); rB.y = (float)fmax(aB1 + bB, 0.0);
  *(float2*)&xout[(co0 << 10) + (y << 5) + x0] = rA;
  *(float2*)&xout[((co0 + 1) << 10) + (y << 5) + x0] = rB;
}

// ================= 1x1 heads ================================================
__global__ __launch_bounds__(256) void head1x1_k(
    const float* __restrict__ x,
    const float* __restrict__ cls_w, const float* __restrict__ cls_b,
    const float* __restrict__ bbox_w, const float* __restrict__ bbox_b,
    float* __restrict__ out, float* __restrict__ bbox_out)
{
  __shared__ float wl[512];
  const int bid = blockIdx.x;
  const int co = bid >> 2;
  const int px = ((bid & 3) << 8) | threadIdx.x;
  const bool is_cls = co < 18;
  const float* wsrc = is_cls ? (cls_w + co * 512) : (bbox_w + (co - 18) * 512);
  for (int i = threadIdx.x; i < 512; i += 256) wl[i] = wsrc[i];
  __syncthreads();
  double acc0 = 0.0, acc1 = 0.0, acc2 = 0.0, acc3 = 0.0;
  #pragma unroll 4
  for (int c = 0; c < 512; c += 4) {
    acc0 += (double)x[((c + 0) << 10) | px] * (double)wl[c + 0];
    acc1 += (double)x[((c + 1) << 10) | px] * (double)wl[c + 1];
    acc2 += (double)x[((c + 2) << 10) | px] * (double)wl[c + 2];
    acc3 += (double)x[((c + 3) << 10) | px] * (double)wl[c + 3];
  }
  double acc = ((acc0 + acc1) + (acc2 + acc3)) +
               (double)(is_cls ? cls_b[co] : bbox_b[co - 18]);
  if (is_cls)
    out[36864 + (co << 10) + px] = (float)(1.0 / (1.0 + exp(-acc)));
  else
    bbox_out[((co - 18) << 10) + px] = (float)acc;
}

// ============ anchors + box decode + clip + key build =======================
__global__ __launch_bounds__(256) void proposals_k(
    const float* __restrict__ bbox, const int* __restrict__ imgsz,
    const float* __restrict__ out, float* __restrict__ props,
    u64* __restrict__ keys, unsigned* __restrict__ rank)
{
  const int r = blockIdx.x * 256 + threadIdx.x;
  if (r >= 9216) return;
  const float4 d = ((const float4*)bbox)[r];
  const int cell = r / 9, a = r - cell * 9;
  const int ix = cell & 31, iy = cell >> 5;
  const int ri = a / 3, si = a - ri * 3;
  const double ratio = (ri == 0) ? 0.5 : (ri == 1 ? 1.0 : 2.0);
  const double scale = (si == 0) ? 128.0 : (si == 1 ? 256.0 : 512.0);
  const double hr = sqrt(ratio), wr = 1.0 / hr;
  const double bx = nearbyint(wr * scale * 0.5);
  const double by = nearbyint(hr * scale * 0.5);
  const double cx = ix * 16.0, cy = iy * 16.0;
  const double w = 2.0 * bx, hh = 2.0 * by;
  const double pcx = (double)d.x * w + cx;
  const double pcy = (double)d.y * hh + cy;
  const double pw = exp((double)d.z) * w;
  const double ph = exp((double)d.w) * hh;
  const double im = (double)imgsz[0];
  float4 o;
  o.x = (float)fmin(fmax(pcx - 0.5 * pw, 0.0), im);
  o.y = (float)fmin(fmax(pcy - 0.5 * ph, 0.0), im);
  o.z = (float)fmin(fmax(pcx + 0.5 * pw, 0.0), im);
  o.w = (float)fmin(fmax(pcy + 0.5 * ph, 0.0), im);
  ((float4*)props)[r] = o;
  const float s = out[36864 + ((2 * (r >> 10) + 1) << 10) + (r & 1023)];
  keys[r] = ((u64)__float_as_uint(s) << 32) | (unsigned)(0x7FFFFFFF - r);
  rank[r] = 0u;
}

// ================= rank sort ================================================
__global__ __launch_bounds__(256) void rank_k(
    const u64* __restrict__ keys, unsigned* __restrict__ rank)
{
  const int jt = blockIdx.x % 36, ic = blockIdx.x / 36;
  const int j = jt * 256 + threadIdx.x;
  const u64 kj = keys[j];
  const int lane = threadIdx.x & 63;
  const int base = ic * 576;
  unsigned lo[9], hi[9];
  #pragma unroll
  for (int rr = 0; rr < 9; ++rr) {
    const u64 k = keys[base + rr * 64 + lane];
    lo[rr] = (unsigned)k; hi[rr] = (unsigned)(k >> 32);
  }
  unsigned cnt = 0;
  #pragma unroll
  for (int rr = 0; rr < 9; ++rr) {
    #pragma unroll
    for (int l = 0; l < 64; ++l) {
      const unsigned llo = (unsigned)__builtin_amdgcn_readlane((int)lo[rr], l);
      const unsigned lhi = (unsigned)__builtin_amdgcn_readlane((int)hi[rr], l);
      const u64 ki = ((u64)lhi << 32) | llo;
      cnt += (ki > kj) ? 1u : 0u;
    }
  }
  atomicAdd(&rank[j], cnt);
}

// ================= scatter into sorted order ================================
__global__ __launch_bounds__(256) void scatter_k(
    const u64* __restrict__ keys, const unsigned* __restrict__ rank,
    const float* __restrict__ props, u64* __restrict__ skeys,
    float4* __restrict__ sboxes)
{
  const int r = blockIdx.x * 256 + threadIdx.x;
  if (r >= 9216) return;
  const unsigned rk = rank[r];
  skeys[rk] = keys[r];
  sboxes[rk] = ((const float4*)props)[r];
}

// ====== suppression bitmask (chunk 64, LDS boxes) ===========================
__global__ __launch_bounds__(256) void mask_k(
    const float4* __restrict__ sb4, u64* __restrict__ mask)
{
  __shared__ __align__(16) float4 ib[64];
  const int ci = blockIdx.x;                  // 0..143
  const int Wb = blockIdx.y << 2;
  const int i_lo = ci << 6;
  const int i_hi = min(i_lo + 64, (Wb + 4) << 6);
  if (i_lo >= i_hi) return;                   // uniform across block
  const int wv = threadIdx.x >> 6, lane = threadIdx.x & 63;
  const int W = Wb + wv;
  const int cnt = i_hi - i_lo;
  if (threadIdx.x < cnt) ib[threadIdx.x] = sb4[i_lo + threadIdx.x];
  __syncthreads();
  const float4 bj = sb4[(W << 6) + lane];
  const float areaJ = (bj.z - bj.x) * (bj.w - bj.y);
  const int n = i_hi - i_lo;
  #pragma unroll 8
  for (int k = 0; k < n; ++k) {
    const float4 bi = ib[k];
    const float areaI = (bi.z - bi.x) * (bi.w - bi.y);
    const float ix1 = fmaxf(bj.x, bi.x), iy1 = fmaxf(bj.y, bi.y);
    const float ix2 = fminf(bj.z, bi.z), iy2 = fminf(bj.w, bi.w);
    const float iw = fmaxf(ix2 - ix1, 0.0f), ih = fmaxf(iy2 - iy1, 0.0f);
    const double inter = (double)iw * (double)ih;
    const double uni = (double)areaJ + (double)areaI - inter + 1e-9;
    const bool pred = inter > 0.3 * uni;
    const u64 bal = __ballot(pred);
    const int i = i_lo + k;
    if (lane == 0) mask[(size_t)i * 144 + W] = bal;
  }
}

// ====== sweep v8: one barrier per sg; delta-pull fused into wave0 ===========
__global__ __launch_bounds__(1024) void sweep_out_k(
    const u64* __restrict__ mask, const u64* __restrict__ skeys,
    const float4* __restrict__ sboxes, float* __restrict__ out)
{
  extern __shared__ __align__(16) char sm[];
  u64* subm   = (u64*)sm;                        // 2*4608 u64 = 73,728 B
  u64* supS   = subm + 9216;                     // 2*8 u64    = 128 B
  u64* keptS  = supS + 16;                       // 144 u64    = 1,152 B
  unsigned short* kpl = (unsigned short*)(keptS + 144);  // 9216 u16 = 18,432 B
  int* kcnt  = (int*)(kpl + 9216);               // 4 B   (total 93,444)

  const int tid = threadIdx.x;
  const int lane = tid & 63, wv = tid >> 6;
  if (tid == 0) *kcnt = 0;
  if (tid < 144) keptS[tid] = 0ULL;
  if (tid < 16) supS[tid] = 0ULL;
  // stage sg 0 into buffer 0 (rows 0..511, words 0..7, stride 9)
  if (tid < 512) {
    const int wq = tid & 7, r0 = tid >> 3;
    #pragma unroll
    for (int k = 0; k < 8; ++k) {
      const int i = r0 + (k << 6);
      subm[i * 9 + wq] = mask[(size_t)i * 144 + wq];
    }
  }
  __syncthreads();

  int Kpp = 0, Kp = 0;                           // wave0-only registers

  for (int sg = 0; sg < 18; ++sg) {
    const int buf = sg & 1, nb = buf ^ 1;
    const int wbase = sg << 3;
    const int ibase = wbase << 6;
    if (wv == 0) {
      // ---- delta-pull: rows [Kpp,Kp) x words(sg), no barrier needed ----
      u64 dacc = 0ULL;
      {
        const int wq = lane & 7;
        int j = Kpp + (lane >> 3);
        for (; j + 24 < Kp; j += 32) {
          const u64 a0 = mask[(size_t)kpl[j +  0] * 144 + wbase + wq];
          const u64 a1 = mask[(size_t)kpl[j +  8] * 144 + wbase + wq];
          const u64 a2 = mask[(size_t)kpl[j + 16] * 144 + wbase + wq];
          const u64 a3 = mask[(size_t)kpl[j + 24] * 144 + wbase + wq];
          dacc |= (a0 | a1) | (a2 | a3);
        }
        for (; j < Kp; j += 8)
          dacc |= mask[(size_t)kpl[j] * 144 + wbase + wq];
      }
      dacc |= __shfl_xor(dacc, 8, 64);
      dacc |= __shfl_xor(dacc, 16, 64);
      dacc |= __shfl_xor(dacc, 32, 64);          // lane l: OR for word l&7
      u64 myAlive = (lane < 8) ? ~(supS[(buf << 3) + lane] | dacc) : 0ULL;
      if (lane < 8) supS[(buf << 3) + lane] = 0ULL;  // ready for sg+2 pre-pull
      const u64* sub = subm + buf * 4608;
      // preload all 8 diagonal rowL words (independent ds_reads)
      u64 rowL8[8];
      #pragma unroll
      for (int w = 0; w < 8; ++w)
        rowL8[w] = sub[((w << 6) + lane) * 9 + w];
      int Kcur = Kp;
      #pragma unroll
      for (int w = 0; w < 8; ++w) {
        const u64 av = __shfl(myAlive, w, 64);
        if (av == 0ULL) continue;
        const u64 rowL = rowL8[w];
        u64 cand = av, keptw = 0ULL;
        while (cand) {
          const int b = (int)__builtin_ctzll(cand);   // uniform
          keptw |= 1ULL << b;
          const u64 sup =
              ((u64)(unsigned)__builtin_amdgcn_readlane((int)(rowL >> 32), b)
               << 32) |
              (unsigned)__builtin_amdgcn_readlane((int)rowL, b);
          cand &= ~(sup | (1ULL << b));
        }
        if (lane == 0) keptS[wbase + w] = keptw;
        if (keptw) {
          if ((keptw >> lane) & 1ULL) {
            const int pre =
                __builtin_popcountll(keptw & ((1ULL << lane) - 1ULL));
            kpl[Kcur + pre] = (unsigned short)(ibase + (w << 6) + lane);
          }
          Kcur += __builtin_popcountll(keptw);
          // apply kept rows to later words of this sg (batch 8 per round)
          u64 t = keptw;
          while (t) {
            int bs[8]; int nn = 0;
            #pragma unroll
            for (int s = 0; s < 8; ++s) {
              if (t) { bs[s] = (int)__builtin_ctzll(t); t &= t - 1ULL; nn = s + 1; }
              else bs[s] = 0;
            }
            const int kk = lane >> 3, wq = lane & 7;
            u64 r = (kk < nn) ? sub[((w << 6) + bs[kk]) * 9 + wq] : 0ULL;
            r |= __shfl_down(r, 8, 64);
            r |= __shfl_down(r, 16, 64);
            r |= __shfl_down(r, 32, 64);
            myAlive &= ~r;                       // lanes 0..7 hold the OR
          }
        }
      }
      Kpp = Kp; Kp = Kcur;
      if (lane == 0) *kcnt = Kcur;               // publish once, pre-barrier
    } else if (wv < 12) {                        // pre-pull(sg+1): rows [0,Kh)
      if (sg + 1 < 18) {
        const int Kh = *kcnt;                    // either old or new K: benign
        const int t6 = tid - 64;                 // 0..703
        const int wq = t6 & 7, str = t6 >> 3;    // 88 streams x 8 words
        const int wb2 = (sg + 1) << 3;
        u64 acc = 0ULL;
        int j = str;
        for (; j + 3 * 88 < Kh; j += 4 * 88) {
          const u64 a0 = mask[(size_t)kpl[j + 0 * 88] * 144 + wb2 + wq];
          const u64 a1 = mask[(size_t)kpl[j + 1 * 88] * 144 + wb2 + wq];
          const u64 a2 = mask[(size_t)kpl[j + 2 * 88] * 144 + wb2 + wq];
          const u64 a3 = mask[(size_t)kpl[j + 3 * 88] * 144 + wb2 + wq];
          acc |= (a0 | a1) | (a2 | a3);
        }
        for (; j < Kh; j += 88)
          acc |= mask[(size_t)kpl[j] * 144 + wb2 + wq];
        if (acc) {
          atomicOr((unsigned*)&supS[(nb << 3) + wq], (unsigned)acc);
          atomicOr(((unsigned*)&supS[(nb << 3) + wq]) + 1, (unsigned)(acc >> 32));
        }
      }
    } else if (sg + 1 < 18) {                    // stage(sg+1) into subm[nb]
      const int s = tid - 768;                   // 0..255
      const int wq = s & 7, r0 = s >> 3;         // 32 rows x 16 iters
      const int ib2 = (sg + 1) << 9;
      const int wb2 = (sg + 1) << 3;
      #pragma unroll
      for (int k = 0; k < 16; ++k) {
        const int i = r0 + (k << 5);
        subm[nb * 4608 + i * 9 + wq] = mask[(size_t)(ib2 + i) * 144 + wb2 + wq];
      }
    }
    __syncthreads();                             // orders everything per sg
  }
  for (int i = tid; i < 9216; i += 1024) {
    const u64 key = skeys[i];
    const int orig = 0x7FFFFFFF - (int)(unsigned)(key & 0xFFFFFFFFULL);
    const bool kp = (keptS[i >> 6] >> (i & 63)) & 1ULL;
    float4 ob = sboxes[i];
    if (!kp) { ob.x = 0.f; ob.y = 0.f; ob.z = 0.f; ob.w = 0.f; }
    ((float4*)out)[orig] = ob;
    out[55296 + orig] = kp ? 1.0f : 0.0f;
  }
}

// ================= fallback NMS (small ws) ==================================
__global__ __launch_bounds__(1024) void nms_fallback_k(
    const float* __restrict__ props, float* __restrict__ out)
{
  __shared__ u64 wmax[16];
  __shared__ float4 curBoxS;
  const int tid = threadIdx.x, wid = tid >> 6, lane = tid & 63;
  u64 key[9];
  float4 box[9];
  #pragma unroll
  for (int j = 0; j < 9; ++j) {
    const int r = tid + (j << 10);
    box[j] = ((const float4*)props)[r];
    const float s = out[36864 + ((2 * (r >> 10) + 1) << 10) + (r & 1023)];
    key[j] = ((u64)__float_as_uint(s) << 32) | (unsigned)(0x7FFFFFFF - r);
  }
  unsigned kept = 0;
  for (;;) {
    u64 m = key[0];
    #pragma unroll
    for (int j = 1; j < 9; ++j) m = key[j] > m ? key[j] : m;
    #pragma unroll
    for (int off = 32; off; off >>= 1) {
      const u64 o = __shfl_down(m, off, 64);
      if (o > m) m = o;
    }
    if (lane == 0) wmax[wid] = m;
    __syncthreads();
    u64 K = wmax[0];
    #pragma unroll
    for (int wv2 = 1; wv2 < 16; ++wv2) { const u64 t = wmax[wv2]; if (t > K) K = t; }
    if (K == 0) break;
    #pragma unroll
    for (int j = 0; j < 9; ++j)
      if (key[j] == K) { curBoxS = box[j]; key[j] = 0; kept |= 1u << j; }
    __syncthreads();
    const float4 cb = curBoxS;
    const float areaC = (cb.z - cb.x) * (cb.w - cb.y);
    #pragma unroll
    for (int j = 0; j < 9; ++j) {
      if (key[j]) {
        const float4 b = box[j];
        const float ix1 = fmaxf(b.x, cb.x), iy1 = fmaxf(b.y, cb.y);
        const float ix2 = fminf(b.z, cb.z), iy2 = fminf(b.w, cb.w);
        const float iw = fmaxf(ix2 - ix1, 0.0f), ih = fmaxf(iy2 - iy1, 0.0f);
        const float areaB = (b.z - b.x) * (b.w - b.y);
        const double inter = (double)iw * (double)ih;
        const double uni = (double)areaB + (double)areaC - inter + 1e-9;
        if (inter > 0.3 * uni) key[j] = 0;
      }
    }
    __syncthreads();
  }
  #pragma unroll
  for (int j = 0; j < 9; ++j) {
    const int r = tid + (j << 10);
    const bool kp = (kept >> j) & 1u;
    float4 ob = box[j];
    if (!kp) { ob.x = 0.f; ob.y = 0.f; ob.z = 0.f; ob.w = 0.f; }
    ((float4*)out)[r] = ob;
    out[55296 + r] = kp ? 1.0f : 0.0f;
  }
}

// ============================================================================
extern "C" void kernel_launch(void* const* d_in, const int* in_sizes, int n_in,
                              void* d_out, int out_size, void* d_ws, size_t ws_size,
                              hipStream_t stream)
{
  const float* feat   = (const float*)d_in[0];
  const int*   imgsz  = (const int*)d_in[1];
  const float* conv_w = (const float*)d_in[2];
  const float* conv_b = (const float*)d_in[3];
  const float* cls_w  = (const float*)d_in[4];
  const float* cls_b  = (const float*)d_in[5];
  const float* bbox_w = (const float*)d_in[6];
  const float* bbox_b = (const float*)d_in[7];
  float* out = (float*)d_out;
  char*  ws  = (char*)d_ws;
  float* x      = (float*)(ws + X_B);
  float* bbox   = (float*)(ws + BBOX_B);
  float* props  = (float*)(ws + PROPS_B);
  u64*      keys  = (u64*)(ws + KEYS_B);
  unsigned* rankp = (unsigned*)(ws + RANK_B);
  u64*      skeys = (u64*)(ws + SKEYS_B);
  float4*   sboxs = (float4*)(ws + SBOX_B);
  u64*      maskp = (u64*)(ws + MASK_B);

  if (ws_size >= (size_t)WS_NEED) {
    hipLaunchKernelGGL(conv3x3_mfma_k, dim3(512), dim3(256), 0, stream,
                       feat, conv_w, conv_b, x);
    hipLaunchKernelGGL(head1x1_k, dim3(216), dim3(256), 0, stream,
                       x, cls_w, cls_b, bbox_w, bbox_b, out, bbox);
    hipLaunchKernelGGL(proposals_k, dim3(36), dim3(256), 0, stream,
                       bbox, imgsz, out, props, keys, rankp);
    hipLaunchKernelGGL(rank_k, dim3(576), dim3(256), 0, stream, keys, rankp);
    hipLaunchKernelGGL(scatter_k, dim3(36), dim3(256), 0, stream,
                       keys, rankp, props, skeys, sboxs);
    hipLaunchKernelGGL(mask_k, dim3(144, 36), dim3(256), 0, stream,
                       sboxs, maskp);
    hipLaunchKernelGGL(sweep_out_k, dim3(1), dim3(1024), 93444, stream,
                       maskp, skeys, sboxs, out);
  } else {
    hipLaunchKernelGGL(conv3x3_relu_fb_k, dim3(512), dim3(256), 0, stream,
                       feat, conv_w, conv_b, x);
    hipLaunchKernelGGL(head1x1_k, dim3(216), dim3(256), 0, stream,
                       x, cls_w, cls_b, bbox_w, bbox_b, out, bbox);
    hipLaunchKernelGGL(proposals_k, dim3(36), dim3(256), 0, stream,
                       bbox, imgsz, out, props, keys, rankp);
    hipLaunchKernelGGL(nms_fallback_k, dim3(1), dim3(1024), 0, stream,
                       props, out);
  }
}

// Round 10
// 254.797 us; speedup vs baseline: 1.0444x; 1.0444x over previous
//
#include <hip/hip_runtime.h>
#include <math.h>

// ---------------- workspace layout (bytes) ----------------
#define X_B      0         // 512*1024 f32   = 2,097,152
#define BBOX_B   2097152   // 36*1024 f32    = 147,456
#define PROPS_B  2244608   // 9216 float4    = 147,456
#define KEYS_B   2392064   // 9216 u64       = 73,728
#define RANK_B   2465792   // 9216 u32       = 36,864
#define SKEYS_B  2502656   // 9216 u64       = 73,728
#define SBOX_B   2576384   // 9216 float4    = 147,456
#define MASK_B   2725888   // 9216*144 u64   = 10,616,832 (end 13,342,720)
#define WS_NEED  13400000

typedef unsigned long long u64;
typedef double v4d __attribute__((ext_vector_type(4)));

// ================= conv 3x3 (256->512, 32x32, pad 1) + ReLU =================
// R10: REVERT to R6 structure (R9's reg-held pipeline spilled: WRITE_SIZE
// 99MB of scratch traffic). Two tweaks, neither extends live ranges across
// the MFMA section:
//  * staging batched: all 17 global loads issued first, then all LDS stores
//    (regs die at the stores -> no spill; one latency exposure per chunk).
//  * s_setprio(1) around the MFMA cluster (2 indep blocks/CU -> phase
//    diversity, T5 regime).
// Layout as R6: wl pitch 580 (=4 mod 32), fl pitch 137 (odd) -> ~2-way max
// conflicts; XCD-aware remap; 4 indep MFMA chains. D row = q+4*reg (probe).
__global__ __launch_bounds__(256, 2) void conv3x3_mfma_k(
    const float* __restrict__ feat, const float* __restrict__ w,
    const float* __restrict__ bias, float* __restrict__ xout)
{
  __shared__ float wl[9280];   // [co][580 pitch] raw chunk weights  37,120 B
  __shared__ float fl[8768];   // [ci][137 pitch]: 4 rows x 34 + pad 35,072 B

  const int tid = threadIdx.x;
  const int bid = blockIdx.x;
  const int ct = ((bid & 7) << 2) | ((bid >> 3) >> 4);   // co-tile 0..31
  const int g  = (bid >> 3) & 15;                        // px-group 0..15
  const int co0 = ct << 4;
  const int y0  = g << 1;

  for (int i = tid; i < 8768; i += 256) fl[i] = 0.0f;

  const int lane = tid & 63, wv = tid >> 6;
  const int q = lane >> 4, n = lane & 15;
  const int wy = wv >> 1, xb = (wv & 1) << 4;
  const int xn = xb + n;

  v4d ac0 = {0.0, 0.0, 0.0, 0.0}, ac1 = {0.0, 0.0, 0.0, 0.0};
  v4d ac2 = {0.0, 0.0, 0.0, 0.0}, ac3 = {0.0, 0.0, 0.0, 0.0};
  const float4* feat4 = (const float4*)feat;

  __syncthreads();

  for (int c = 0; c < 4; ++c) {
    const int cb = c << 6;
    // ---- issue ALL 17 independent global loads first ----
    float4 wr[9];
    #pragma unroll
    for (int i = 0; i < 9; ++i) {
      const int idx4 = tid + (i << 8);
      const int co = idx4 / 144;
      const int s4 = idx4 - co * 144;
      wr[i] = *(const float4*)(w + (co0 + co) * 2304 + c * 576 + (s4 << 2));
    }
    float4 fr[8];
    bool fv[8];
    #pragma unroll
    for (int i = 0; i < 8; ++i) {
      const int idx4 = tid + (i << 8);
      const int ci = idx4 >> 5;
      const int rr = (idx4 >> 3) & 3;
      const int x4 = idx4 & 7;
      const int grow = y0 - 1 + rr;
      fv[i] = ((unsigned)grow < 32u);
      if (fv[i]) fr[i] = feat4[((cb + ci) << 8) + (grow << 3) + x4];
    }
    // ---- then all LDS stores (regs die here, before compute) ----
    #pragma unroll
    for (int i = 0; i < 9; ++i) {
      const int idx4 = tid + (i << 8);
      const int co = idx4 / 144;
      const int s4 = idx4 - co * 144;
      *(float4*)&wl[co * 580 + (s4 << 2)] = wr[i];
    }
    #pragma unroll
    for (int i = 0; i < 8; ++i) {
      const int idx4 = tid + (i << 8);
      const int ci = idx4 >> 5;
      const int rr = (idx4 >> 3) & 3;
      const int x4 = idx4 & 7;
      if (fv[i]) {
        float* p = &fl[ci * 137 + rr * 34 + 1 + (x4 << 2)];
        p[0] = fr[i].x; p[1] = fr[i].y; p[2] = fr[i].z; p[3] = fr[i].w;
      }
    }
    __syncthreads();
    // ---- compute: 9 taps x 16 mfma (K=64), 4 indep chains ----
    __builtin_amdgcn_s_setprio(1);
    #pragma unroll
    for (int tap = 0; tap < 9; ++tap) {
      const int ky = tap / 3, kx = tap - 3 * (tap / 3);
      const float* ab = &wl[n * 580 + q * 9 + tap];                // + u*36
      const float* bb = &fl[q * 137 + (wy + ky) * 34 + xn + kx];   // + u*548
      #pragma unroll
      for (int u = 0; u < 16; u += 4) {
        ac0 = __builtin_amdgcn_mfma_f64_16x16x4f64(
            (double)ab[(u + 0) * 36], (double)bb[(u + 0) * 548], ac0, 0, 0, 0);
        ac1 = __builtin_amdgcn_mfma_f64_16x16x4f64(
            (double)ab[(u + 1) * 36], (double)bb[(u + 1) * 548], ac1, 0, 0, 0);
        ac2 = __builtin_amdgcn_mfma_f64_16x16x4f64(
            (double)ab[(u + 2) * 36], (double)bb[(u + 2) * 548], ac2, 0, 0, 0);
        ac3 = __builtin_amdgcn_mfma_f64_16x16x4f64(
            (double)ab[(u + 3) * 36], (double)bb[(u + 3) * 548], ac3, 0, 0, 0);
      }
    }
    __builtin_amdgcn_s_setprio(0);
    __syncthreads();
  }

  // epilogue: D[m][n] with m = q + 4*i (probe-verified), n = px col
  const int pbase = (g << 6) + (wv << 4) + n;
  #pragma unroll
  for (int i = 0; i < 4; ++i) {
    const int co = co0 + q + (i << 2);
    const double s = (ac0[i] + ac1[i]) + (ac2[i] + ac3[i]);
    const double v = fmax(s + (double)bias[co], 0.0);
    xout[(co << 10) + pbase] = (float)v;
  }
}

// ========== fallback conv (small ws) ========================================
#define CPITCH 38
#define CCHS   (18 * CPITCH)
__global__ __launch_bounds__(256) void conv3x3_relu_fb_k(
    const float* __restrict__ feat, const float* __restrict__ w,
    const float* __restrict__ bias, float* __restrict__ xout)
{
  __shared__ float il[2][8 * CCHS];
  const int cp = blockIdx.x >> 1, h = blockIdx.x & 1;
  const int tid = threadIdx.x;
  const int h16 = h << 4;
  const int co0 = cp << 1;
  for (int i = tid; i < 8 * CCHS; i += 256) { il[0][i] = 0.0f; il[1][i] = 0.0f; }
  const int yl = tid >> 4;
  const int x0 = (tid & 15) << 1;
  double aA0 = 0.0, aA1 = 0.0, aB0 = 0.0, aB1 = 0.0;
  const float4* feat4 = (const float4*)feat;
  float4 pf[5]; int pch[5], pt[5], pc4[5], pok[5];
  #pragma unroll
  for (int k = 0; k < 5; ++k) {
    const int i = tid + (k << 8);
    const int ch = i / 144, rem = i - ch * 144;
    const int t = rem >> 3, c4 = rem & 7;
    const int g = h16 - 1 + t;
    pch[k] = ch; pt[k] = t; pc4[k] = c4;
    pok[k] = (i < 1152) && ((unsigned)g < 32u);
    pf[k] = pok[k] ? feat4[(ch << 8) + (g << 3) + c4] : float4{0.f,0.f,0.f,0.f};
  }
  __syncthreads();
  for (int cc = 0; cc < 256; cc += 8) {
    const int buf = (cc >> 3) & 1;
    #pragma unroll
    for (int k = 0; k < 5; ++k)
      if (pok[k]) {
        float* p = &il[buf][pch[k] * CCHS + pt[k] * CPITCH + (pc4[k] << 2) + 1];
        p[0] = pf[k].x; p[1] = pf[k].y; p[2] = pf[k].z; p[3] = pf[k].w;
      }
    if (cc + 8 < 256) {
      #pragma unroll
      for (int k = 0; k < 5; ++k) {
        const int g = h16 - 1 + pt[k];
        if (pok[k]) pf[k] = feat4[((cc + 8 + pch[k]) << 8) + (g << 3) + pc4[k]];
      }
    }
    __syncthreads();
    #pragma unroll
    for (int cl = 0; cl < 8; ++cl) {
      const float* wAp = w + co0 * 2304 + (cc + cl) * 9;
      const float* wBp = wAp + 2304;
      double wa[9], wb[9];
      #pragma unroll
      for (int q = 0; q < 9; ++q) { wa[q] = (double)wAp[q]; wb[q] = (double)wBp[q]; }
      const float* ir = &il[buf][cl * CCHS + yl * CPITCH + x0];
      #pragma unroll
      for (int ky = 0; ky < 3; ++ky) {
        const float2 q0 = *(const float2*)(ir + ky * CPITCH);
        const float2 q1 = *(const float2*)(ir + ky * CPITCH + 2);
        const double v0 = (double)q0.x, v1 = (double)q0.y;
        const double v2 = (double)q1.x, v3 = (double)q1.y;
        aA0 += v0 * wa[3*ky+0] + v1 * wa[3*ky+1] + v2 * wa[3*ky+2];
        aA1 += v1 * wa[3*ky+0] + v2 * wa[3*ky+1] + v3 * wa[3*ky+2];
        aB0 += v0 * wb[3*ky+0] + v1 * wb[3*ky+1] + v2 * wb[3*ky+2];
        aB1 += v1 * wb[3*ky+0] + v2 * wb[3*ky+1] + v3 * wb[3*ky+2];
      }
    }
  }
  const double bA = (double)bias[co0], bB = (double)bias[co0 + 1];
  const int y = h16 + yl;
  float2 rA, rB;
  rA.x = (float)fmax(aA0 + bA, 0.0); rA.y = (float)fmax(aA1 + bA, 0.0);
  rB.x = (float)fmax(aB0 + bB, 0.0); rB.y = (float)fmax(aB1 + bB, 0.0);
  *(float2*)&xout[(co0 << 10) + (y << 5) + x0] = rA;
  *(float2*)&xout[((co0 + 1) << 10) + (y << 5) + x0] = rB;
}

// ================= 1x1 heads ================================================
__global__ __launch_bounds__(256) void head1x1_k(
    const float* __restrict__ x,
    const float* __restrict__ cls_w, const float* __restrict__ cls_b,
    const float* __restrict__ bbox_w, const float* __restrict__ bbox_b,
    float* __restrict__ out, float* __restrict__ bbox_out)
{
  __shared__ float wl[512];
  const int bid = blockIdx.x;
  const int co = bid >> 2;
  const int px = ((bid & 3) << 8) | threadIdx.x;
  const bool is_cls = co < 18;
  const float* wsrc = is_cls ? (cls_w + co * 512) : (bbox_w + (co - 18) * 512);
  for (int i = threadIdx.x; i < 512; i += 256) wl[i] = wsrc[i];
  __syncthreads();
  double acc0 = 0.0, acc1 = 0.0, acc2 = 0.0, acc3 = 0.0;
  #pragma unroll 4
  for (int c = 0; c < 512; c += 4) {
    acc0 += (double)x[((c + 0) << 10) | px] * (double)wl[c + 0];
    acc1 += (double)x[((c + 1) << 10) | px] * (double)wl[c + 1];
    acc2 += (double)x[((c + 2) << 10) | px] * (double)wl[c + 2];
    acc3 += (double)x[((c + 3) << 10) | px] * (double)wl[c + 3];
  }
  double acc = ((acc0 + acc1) + (acc2 + acc3)) +
               (double)(is_cls ? cls_b[co] : bbox_b[co - 18]);
  if (is_cls)
    out[36864 + (co << 10) + px] = (float)(1.0 / (1.0 + exp(-acc)));
  else
    bbox_out[((co - 18) << 10) + px] = (float)acc;
}

// ============ anchors + box decode + clip + key build =======================
__global__ __launch_bounds__(256) void proposals_k(
    const float* __restrict__ bbox, const int* __restrict__ imgsz,
    const float* __restrict__ out, float* __restrict__ props,
    u64* __restrict__ keys, unsigned* __restrict__ rank)
{
  const int r = blockIdx.x * 256 + threadIdx.x;
  if (r >= 9216) return;
  const float4 d = ((const float4*)bbox)[r];
  const int cell = r / 9, a = r - cell * 9;
  const int ix = cell & 31, iy = cell >> 5;
  const int ri = a / 3, si = a - ri * 3;
  const double ratio = (ri == 0) ? 0.5 : (ri == 1 ? 1.0 : 2.0);
  const double scale = (si == 0) ? 128.0 : (si == 1 ? 256.0 : 512.0);
  const double hr = sqrt(ratio), wr = 1.0 / hr;
  const double bx = nearbyint(wr * scale * 0.5);
  const double by = nearbyint(hr * scale * 0.5);
  const double cx = ix * 16.0, cy = iy * 16.0;
  const double w = 2.0 * bx, hh = 2.0 * by;
  const double pcx = (double)d.x * w + cx;
  const double pcy = (double)d.y * hh + cy;
  const double pw = exp((double)d.z) * w;
  const double ph = exp((double)d.w) * hh;
  const double im = (double)imgsz[0];
  float4 o;
  o.x = (float)fmin(fmax(pcx - 0.5 * pw, 0.0), im);
  o.y = (float)fmin(fmax(pcy - 0.5 * ph, 0.0), im);
  o.z = (float)fmin(fmax(pcx + 0.5 * pw, 0.0), im);
  o.w = (float)fmin(fmax(pcy + 0.5 * ph, 0.0), im);
  ((float4*)props)[r] = o;
  const float s = out[36864 + ((2 * (r >> 10) + 1) << 10) + (r & 1023)];
  keys[r] = ((u64)__float_as_uint(s) << 32) | (unsigned)(0x7FFFFFFF - r);
  rank[r] = 0u;
}

// ================= rank sort ================================================
__global__ __launch_bounds__(256) void rank_k(
    const u64* __restrict__ keys, unsigned* __restrict__ rank)
{
  const int jt = blockIdx.x % 36, ic = blockIdx.x / 36;
  const int j = jt * 256 + threadIdx.x;
  const u64 kj = keys[j];
  const int lane = threadIdx.x & 63;
  const int base = ic * 576;
  unsigned lo[9], hi[9];
  #pragma unroll
  for (int rr = 0; rr < 9; ++rr) {
    const u64 k = keys[base + rr * 64 + lane];
    lo[rr] = (unsigned)k; hi[rr] = (unsigned)(k >> 32);
  }
  unsigned cnt = 0;
  #pragma unroll
  for (int rr = 0; rr < 9; ++rr) {
    #pragma unroll
    for (int l = 0; l < 64; ++l) {
      const unsigned llo = (unsigned)__builtin_amdgcn_readlane((int)lo[rr], l);
      const unsigned lhi = (unsigned)__builtin_amdgcn_readlane((int)hi[rr], l);
      const u64 ki = ((u64)lhi << 32) | llo;
      cnt += (ki > kj) ? 1u : 0u;
    }
  }
  atomicAdd(&rank[j], cnt);
}

// ================= scatter into sorted order ================================
__global__ __launch_bounds__(256) void scatter_k(
    const u64* __restrict__ keys, const unsigned* __restrict__ rank,
    const float* __restrict__ props, u64* __restrict__ skeys,
    float4* __restrict__ sboxes)
{
  const int r = blockIdx.x * 256 + threadIdx.x;
  if (r >= 9216) return;
  const unsigned rk = rank[r];
  skeys[rk] = keys[r];
  sboxes[rk] = ((const float4*)props)[r];
}

// ====== suppression bitmask (chunk 64, LDS boxes) ===========================
__global__ __launch_bounds__(256) void mask_k(
    const float4* __restrict__ sb4, u64* __restrict__ mask)
{
  __shared__ __align__(16) float4 ib[64];
  const int ci = blockIdx.x;                  // 0..143
  const int Wb = blockIdx.y << 2;
  const int i_lo = ci << 6;
  const int i_hi = min(i_lo + 64, (Wb + 4) << 6);
  if (i_lo >= i_hi) return;                   // uniform across block
  const int wv = threadIdx.x >> 6, lane = threadIdx.x & 63;
  const int W = Wb + wv;
  const int cnt = i_hi - i_lo;
  if (threadIdx.x < cnt) ib[threadIdx.x] = sb4[i_lo + threadIdx.x];
  __syncthreads();
  const float4 bj = sb4[(W << 6) + lane];
  const float areaJ = (bj.z - bj.x) * (bj.w - bj.y);
  const int n = i_hi - i_lo;
  #pragma unroll 8
  for (int k = 0; k < n; ++k) {
    const float4 bi = ib[k];
    const float areaI = (bi.z - bi.x) * (bi.w - bi.y);
    const float ix1 = fmaxf(bj.x, bi.x), iy1 = fmaxf(bj.y, bi.y);
    const float ix2 = fminf(bj.z, bi.z), iy2 = fminf(bj.w, bi.w);
    const float iw = fmaxf(ix2 - ix1, 0.0f), ih = fmaxf(iy2 - iy1, 0.0f);
    const double inter = (double)iw * (double)ih;
    const double uni = (double)areaJ + (double)areaI - inter + 1e-9;
    const bool pred = inter > 0.3 * uni;
    const u64 bal = __ballot(pred);
    const int i = i_lo + k;
    if (lane == 0) mask[(size_t)i * 144 + W] = bal;
  }
}

// ====== sweep v8: one barrier per sg; delta-pull fused into wave0 ===========
__global__ __launch_bounds__(1024) void sweep_out_k(
    const u64* __restrict__ mask, const u64* __restrict__ skeys,
    const float4* __restrict__ sboxes, float* __restrict__ out)
{
  extern __shared__ __align__(16) char sm[];
  u64* subm   = (u64*)sm;                        // 2*4608 u64 = 73,728 B
  u64* supS   = subm + 9216;                     // 2*8 u64    = 128 B
  u64* keptS  = supS + 16;                       // 144 u64    = 1,152 B
  unsigned short* kpl = (unsigned short*)(keptS + 144);  // 9216 u16 = 18,432 B
  int* kcnt  = (int*)(kpl + 9216);               // 4 B   (total 93,444)

  const int tid = threadIdx.x;
  const int lane = tid & 63, wv = tid >> 6;
  if (tid == 0) *kcnt = 0;
  if (tid < 144) keptS[tid] = 0ULL;
  if (tid < 16) supS[tid] = 0ULL;
  // stage sg 0 into buffer 0 (rows 0..511, words 0..7, stride 9)
  if (tid < 512) {
    const int wq = tid & 7, r0 = tid >> 3;
    #pragma unroll
    for (int k = 0; k < 8; ++k) {
      const int i = r0 + (k << 6);
      subm[i * 9 + wq] = mask[(size_t)i * 144 + wq];
    }
  }
  __syncthreads();

  int Kpp = 0, Kp = 0;                           // wave0-only registers

  for (int sg = 0; sg < 18; ++sg) {
    const int buf = sg & 1, nb = buf ^ 1;
    const int wbase = sg << 3;
    const int ibase = wbase << 6;
    if (wv == 0) {
      // ---- delta-pull: rows [Kpp,Kp) x words(sg), no barrier needed ----
      u64 dacc = 0ULL;
      {
        const int wq = lane & 7;
        int j = Kpp + (lane >> 3);
        for (; j + 24 < Kp; j += 32) {
          const u64 a0 = mask[(size_t)kpl[j +  0] * 144 + wbase + wq];
          const u64 a1 = mask[(size_t)kpl[j +  8] * 144 + wbase + wq];
          const u64 a2 = mask[(size_t)kpl[j + 16] * 144 + wbase + wq];
          const u64 a3 = mask[(size_t)kpl[j + 24] * 144 + wbase + wq];
          dacc |= (a0 | a1) | (a2 | a3);
        }
        for (; j < Kp; j += 8)
          dacc |= mask[(size_t)kpl[j] * 144 + wbase + wq];
      }
      dacc |= __shfl_xor(dacc, 8, 64);
      dacc |= __shfl_xor(dacc, 16, 64);
      dacc |= __shfl_xor(dacc, 32, 64);          // lane l: OR for word l&7
      u64 myAlive = (lane < 8) ? ~(supS[(buf << 3) + lane] | dacc) : 0ULL;
      if (lane < 8) supS[(buf << 3) + lane] = 0ULL;  // ready for sg+2 pre-pull
      const u64* sub = subm + buf * 4608;
      // preload all 8 diagonal rowL words (independent ds_reads)
      u64 rowL8[8];
      #pragma unroll
      for (int w = 0; w < 8; ++w)
        rowL8[w] = sub[((w << 6) + lane) * 9 + w];
      int Kcur = Kp;
      #pragma unroll
      for (int w = 0; w < 8; ++w) {
        const u64 av = __shfl(myAlive, w, 64);
        if (av == 0ULL) continue;
        const u64 rowL = rowL8[w];
        u64 cand = av, keptw = 0ULL;
        while (cand) {
          const int b = (int)__builtin_ctzll(cand);   // uniform
          keptw |= 1ULL << b;
          const u64 sup =
              ((u64)(unsigned)__builtin_amdgcn_readlane((int)(rowL >> 32), b)
               << 32) |
              (unsigned)__builtin_amdgcn_readlane((int)rowL, b);
          cand &= ~(sup | (1ULL << b));
        }
        if (lane == 0) keptS[wbase + w] = keptw;
        if (keptw) {
          if ((keptw >> lane) & 1ULL) {
            const int pre =
                __builtin_popcountll(keptw & ((1ULL << lane) - 1ULL));
            kpl[Kcur + pre] = (unsigned short)(ibase + (w << 6) + lane);
          }
          Kcur += __builtin_popcountll(keptw);
          // apply kept rows to later words of this sg (batch 8 per round)
          u64 t = keptw;
          while (t) {
            int bs[8]; int nn = 0;
            #pragma unroll
            for (int s = 0; s < 8; ++s) {
              if (t) { bs[s] = (int)__builtin_ctzll(t); t &= t - 1ULL; nn = s + 1; }
              else bs[s] = 0;
            }
            const int kk = lane >> 3, wq = lane & 7;
            u64 r = (kk < nn) ? sub[((w << 6) + bs[kk]) * 9 + wq] : 0ULL;
            r |= __shfl_down(r, 8, 64);
            r |= __shfl_down(r, 16, 64);
            r |= __shfl_down(r, 32, 64);
            myAlive &= ~r;                       // lanes 0..7 hold the OR
          }
        }
      }
      Kpp = Kp; Kp = Kcur;
      if (lane == 0) *kcnt = Kcur;               // publish once, pre-barrier
    } else if (wv < 12) {                        // pre-pull(sg+1): rows [0,Kh)
      if (sg + 1 < 18) {
        const int Kh = *kcnt;                    // either old or new K: benign
        const int t6 = tid - 64;                 // 0..703
        const int wq = t6 & 7, str = t6 >> 3;    // 88 streams x 8 words
        const int wb2 = (sg + 1) << 3;
        u64 acc = 0ULL;
        int j = str;
        for (; j + 3 * 88 < Kh; j += 4 * 88) {
          const u64 a0 = mask[(size_t)kpl[j + 0 * 88] * 144 + wb2 + wq];
          const u64 a1 = mask[(size_t)kpl[j + 1 * 88] * 144 + wb2 + wq];
          const u64 a2 = mask[(size_t)kpl[j + 2 * 88] * 144 + wb2 + wq];
          const u64 a3 = mask[(size_t)kpl[j + 3 * 88] * 144 + wb2 + wq];
          acc |= (a0 | a1) | (a2 | a3);
        }
        for (; j < Kh; j += 88)
          acc |= mask[(size_t)kpl[j] * 144 + wb2 + wq];
        if (acc) {
          atomicOr((unsigned*)&supS[(nb << 3) + wq], (unsigned)acc);
          atomicOr(((unsigned*)&supS[(nb << 3) + wq]) + 1, (unsigned)(acc >> 32));
        }
      }
    } else if (sg + 1 < 18) {                    // stage(sg+1) into subm[nb]
      const int s = tid - 768;                   // 0..255
      const int wq = s & 7, r0 = s >> 3;         // 32 rows x 16 iters
      const int ib2 = (sg + 1) << 9;
      const int wb2 = (sg + 1) << 3;
      #pragma unroll
      for (int k = 0; k < 16; ++k) {
        const int i = r0 + (k << 5);
        subm[nb * 4608 + i * 9 + wq] = mask[(size_t)(ib2 + i) * 144 + wb2 + wq];
      }
    }
    __syncthreads();                             // orders everything per sg
  }
  for (int i = tid; i < 9216; i += 1024) {
    const u64 key = skeys[i];
    const int orig = 0x7FFFFFFF - (int)(unsigned)(key & 0xFFFFFFFFULL);
    const bool kp = (keptS[i >> 6] >> (i & 63)) & 1ULL;
    float4 ob = sboxes[i];
    if (!kp) { ob.x = 0.f; ob.y = 0.f; ob.z = 0.f; ob.w = 0.f; }
    ((float4*)out)[orig] = ob;
    out[55296 + orig] = kp ? 1.0f : 0.0f;
  }
}

// ================= fallback NMS (small ws) ==================================
__global__ __launch_bounds__(1024) void nms_fallback_k(
    const float* __restrict__ props, float* __restrict__ out)
{
  __shared__ u64 wmax[16];
  __shared__ float4 curBoxS;
  const int tid = threadIdx.x, wid = tid >> 6, lane = tid & 63;
  u64 key[9];
  float4 box[9];
  #pragma unroll
  for (int j = 0; j < 9; ++j) {
    const int r = tid + (j << 10);
    box[j] = ((const float4*)props)[r];
    const float s = out[36864 + ((2 * (r >> 10) + 1) << 10) + (r & 1023)];
    key[j] = ((u64)__float_as_uint(s) << 32) | (unsigned)(0x7FFFFFFF - r);
  }
  unsigned kept = 0;
  for (;;) {
    u64 m = key[0];
    #pragma unroll
    for (int j = 1; j < 9; ++j) m = key[j] > m ? key[j] : m;
    #pragma unroll
    for (int off = 32; off; off >>= 1) {
      const u64 o = __shfl_down(m, off, 64);
      if (o > m) m = o;
    }
    if (lane == 0) wmax[wid] = m;
    __syncthreads();
    u64 K = wmax[0];
    #pragma unroll
    for (int wv2 = 1; wv2 < 16; ++wv2) { const u64 t = wmax[wv2]; if (t > K) K = t; }
    if (K == 0) break;
    #pragma unroll
    for (int j = 0; j < 9; ++j)
      if (key[j] == K) { curBoxS = box[j]; key[j] = 0; kept |= 1u << j; }
    __syncthreads();
    const float4 cb = curBoxS;
    const float areaC = (cb.z - cb.x) * (cb.w - cb.y);
    #pragma unroll
    for (int j = 0; j < 9; ++j) {
      if (key[j]) {
        const float4 b = box[j];
        const float ix1 = fmaxf(b.x, cb.x), iy1 = fmaxf(b.y, cb.y);
        const float ix2 = fminf(b.z, cb.z), iy2 = fminf(b.w, cb.w);
        const float iw = fmaxf(ix2 - ix1, 0.0f), ih = fmaxf(iy2 - iy1, 0.0f);
        const float areaB = (b.z - b.x) * (b.w - b.y);
        const double inter = (double)iw * (double)ih;
        const double uni = (double)areaB + (double)areaC - inter + 1e-9;
        if (inter > 0.3 * uni) key[j] = 0;
      }
    }
    __syncthreads();
  }
  #pragma unroll
  for (int j = 0; j < 9; ++j) {
    const int r = tid + (j << 10);
    const bool kp = (kept >> j) & 1u;
    float4 ob = box[j];
    if (!kp) { ob.x = 0.f; ob.y = 0.f; ob.z = 0.f; ob.w = 0.f; }
    ((float4*)out)[r] = ob;
    out[55296 + r] = kp ? 1.0f : 0.0f;
  }
}

// ============================================================================
extern "C" void kernel_launch(void* const* d_in, const int* in_sizes, int n_in,
                              void* d_out, int out_size, void* d_ws, size_t ws_size,
                              hipStream_t stream)
{
  const float* feat   = (const float*)d_in[0];
  const int*   imgsz  = (const int*)d_in[1];
  const float* conv_w = (const float*)d_in[2];
  const float* conv_b = (const float*)d_in[3];
  const float* cls_w  = (const float*)d_in[4];
  const float* cls_b  = (const float*)d_in[5];
  const float* bbox_w = (const float*)d_in[6];
  const float* bbox_b = (const float*)d_in[7];
  float* out = (float*)d_out;
  char*  ws  = (char*)d_ws;
  float* x      = (float*)(ws + X_B);
  float* bbox   = (float*)(ws + BBOX_B);
  float* props  = (float*)(ws + PROPS_B);
  u64*      keys  = (u64*)(ws + KEYS_B);
  unsigned* rankp = (unsigned*)(ws + RANK_B);
  u64*      skeys = (u64*)(ws + SKEYS_B);
  float4*   sboxs = (float4*)(ws + SBOX_B);
  u64*      maskp = (u64*)(ws + MASK_B);

  if (ws_size >= (size_t)WS_NEED) {
    hipLaunchKernelGGL(conv3x3_mfma_k, dim3(512), dim3(256), 0, stream,
                       feat, conv_w, conv_b, x);
    hipLaunchKernelGGL(head1x1_k, dim3(216), dim3(256), 0, stream,
                       x, cls_w, cls_b, bbox_w, bbox_b, out, bbox);
    hipLaunchKernelGGL(proposals_k, dim3(36), dim3(256), 0, stream,
                       bbox, imgsz, out, props, keys, rankp);
    hipLaunchKernelGGL(rank_k, dim3(576), dim3(256), 0, stream, keys, rankp);
    hipLaunchKernelGGL(scatter_k, dim3(36), dim3(256), 0, stream,
                       keys, rankp, props, skeys, sboxs);
    hipLaunchKernelGGL(mask_k, dim3(144, 36), dim3(256), 0, stream,
                       sboxs, maskp);
    hipLaunchKernelGGL(sweep_out_k, dim3(1), dim3(1024), 93444, stream,
                       maskp, skeys, sboxs, out);
  } else {
    hipLaunchKernelGGL(conv3x3_relu_fb_k, dim3(512), dim3(256), 0, stream,
                       feat, conv_w, conv_b, x);
    hipLaunchKernelGGL(head1x1_k, dim3(216), dim3(256), 0, stream,
                       x, cls_w, cls_b, bbox_w, bbox_b, out, bbox);
    hipLaunchKernelGGL(proposals_k, dim3(36), dim3(256), 0, stream,
                       bbox, imgsz, out, props, keys, rankp);
    hipLaunchKernelGGL(nms_fallback_k, dim3(1), dim3(1024), 0, stream,
                       props, out);
  }
}

// Round 11
// 242.936 us; speedup vs baseline: 1.0954x; 1.0488x over previous
//
#include <hip/hip_runtime.h>
#include <math.h>

// ---------------- workspace layout (bytes) ----------------
#define X_B      0         // 512*1024 f32   = 2,097,152
#define BBOX_B   2097152   // 36*1024 f32    = 147,456
#define PROPS_B  2244608   // 9216 float4    = 147,456
#define KEYS_B   2392064   // 9216 u64       = 73,728
#define RANK_B   2465792   // 9216 u32       = 36,864
#define SKEYS_B  2502656   // 9216 u64       = 73,728
#define SBOX_B   2576384   // 9216 float4    = 147,456
#define MASK_B   2725888   // 9216*144 u64   = 10,616,832 (end 13,342,720)
#define WS_NEED  13400000

typedef unsigned long long u64;
typedef double v4d __attribute__((ext_vector_type(4)));

// ================= conv 3x3 (256->512, 32x32, pad 1) + ReLU =================
// R11: exact R8/R6 conv (best verified; R10's batched-staging+setprio was a
// small regression). Raw-pitch-580 weight staging (conflict-free b128),
// pitch-137 features, XCD-aware remap, 4 indep MFMA chains.
// D layout (probe-verified): row = (lane>>4)+4*reg, col = lane&15.
__global__ __launch_bounds__(256, 2) void conv3x3_mfma_k(
    const float* __restrict__ feat, const float* __restrict__ w,
    const float* __restrict__ bias, float* __restrict__ xout)
{
  __shared__ float wl[9280];   // [co][580 pitch] raw chunk weights  37,120 B
  __shared__ float fl[8768];   // [ci][137 pitch]: 4 rows x 34 + pad 35,072 B

  const int tid = threadIdx.x;
  const int bid = blockIdx.x;
  const int ct = ((bid & 7) << 2) | ((bid >> 3) >> 4);   // co-tile 0..31
  const int g  = (bid >> 3) & 15;                        // px-group 0..15
  const int co0 = ct << 4;
  const int y0  = g << 1;

  for (int i = tid; i < 8768; i += 256) fl[i] = 0.0f;

  const int lane = tid & 63, wv = tid >> 6;
  const int q = lane >> 4, n = lane & 15;
  const int wy = wv >> 1, xb = (wv & 1) << 4;
  const int xn = xb + n;

  v4d ac0 = {0.0, 0.0, 0.0, 0.0}, ac1 = {0.0, 0.0, 0.0, 0.0};
  v4d ac2 = {0.0, 0.0, 0.0, 0.0}, ac3 = {0.0, 0.0, 0.0, 0.0};
  const float4* feat4 = (const float4*)feat;

  __syncthreads();

  for (int c = 0; c < 4; ++c) {
    const int cb = c << 6;
    #pragma unroll
    for (int i = 0; i < 9; ++i) {
      const int idx4 = tid + (i << 8);
      const int co = idx4 / 144;
      const int s4 = idx4 - co * 144;
      *(float4*)&wl[co * 580 + (s4 << 2)] =
          *(const float4*)(w + (co0 + co) * 2304 + c * 576 + (s4 << 2));
    }
    #pragma unroll
    for (int i = 0; i < 8; ++i) {
      const int idx4 = tid + (i << 8);
      const int ci = idx4 >> 5;
      const int rr = (idx4 >> 3) & 3;
      const int x4 = idx4 & 7;
      const int grow = y0 - 1 + rr;
      if ((unsigned)grow < 32u) {
        const float4 v = feat4[((cb + ci) << 8) + (grow << 3) + x4];
        float* p = &fl[ci * 137 + rr * 34 + 1 + (x4 << 2)];
        p[0] = v.x; p[1] = v.y; p[2] = v.z; p[3] = v.w;
      }
    }
    __syncthreads();
    #pragma unroll
    for (int tap = 0; tap < 9; ++tap) {
      const int ky = tap / 3, kx = tap - 3 * (tap / 3);
      const float* ab = &wl[n * 580 + q * 9 + tap];                // + u*36
      const float* bb = &fl[q * 137 + (wy + ky) * 34 + xn + kx];   // + u*548
      #pragma unroll
      for (int u = 0; u < 16; u += 4) {
        ac0 = __builtin_amdgcn_mfma_f64_16x16x4f64(
            (double)ab[(u + 0) * 36], (double)bb[(u + 0) * 548], ac0, 0, 0, 0);
        ac1 = __builtin_amdgcn_mfma_f64_16x16x4f64(
            (double)ab[(u + 1) * 36], (double)bb[(u + 1) * 548], ac1, 0, 0, 0);
        ac2 = __builtin_amdgcn_mfma_f64_16x16x4f64(
            (double)ab[(u + 2) * 36], (double)bb[(u + 2) * 548], ac2, 0, 0, 0);
        ac3 = __builtin_amdgcn_mfma_f64_16x16x4f64(
            (double)ab[(u + 3) * 36], (double)bb[(u + 3) * 548], ac3, 0, 0, 0);
      }
    }
    __syncthreads();
  }

  const int pbase = (g << 6) + (wv << 4) + n;
  #pragma unroll
  for (int i = 0; i < 4; ++i) {
    const int co = co0 + q + (i << 2);
    const double s = (ac0[i] + ac1[i]) + (ac2[i] + ac3[i]);
    const double v = fmax(s + (double)bias[co], 0.0);
    xout[(co << 10) + pbase] = (float)v;
  }
}

// ========== fallback conv (small ws) ========================================
#define CPITCH 38
#define CCHS   (18 * CPITCH)
__global__ __launch_bounds__(256) void conv3x3_relu_fb_k(
    const float* __restrict__ feat, const float* __restrict__ w,
    const float* __restrict__ bias, float* __restrict__ xout)
{
  __shared__ float il[2][8 * CCHS];
  const int cp = blockIdx.x >> 1, h = blockIdx.x & 1;
  const int tid = threadIdx.x;
  const int h16 = h << 4;
  const int co0 = cp << 1;
  for (int i = tid; i < 8 * CCHS; i += 256) { il[0][i] = 0.0f; il[1][i] = 0.0f; }
  const int yl = tid >> 4;
  const int x0 = (tid & 15) << 1;
  double aA0 = 0.0, aA1 = 0.0, aB0 = 0.0, aB1 = 0.0;
  const float4* feat4 = (const float4*)feat;
  float4 pf[5]; int pch[5], pt[5], pc4[5], pok[5];
  #pragma unroll
  for (int k = 0; k < 5; ++k) {
    const int i = tid + (k << 8);
    const int ch = i / 144, rem = i - ch * 144;
    const int t = rem >> 3, c4 = rem & 7;
    const int g = h16 - 1 + t;
    pch[k] = ch; pt[k] = t; pc4[k] = c4;
    pok[k] = (i < 1152) && ((unsigned)g < 32u);
    pf[k] = pok[k] ? feat4[(ch << 8) + (g << 3) + c4] : float4{0.f,0.f,0.f,0.f};
  }
  __syncthreads();
  for (int cc = 0; cc < 256; cc += 8) {
    const int buf = (cc >> 3) & 1;
    #pragma unroll
    for (int k = 0; k < 5; ++k)
      if (pok[k]) {
        float* p = &il[buf][pch[k] * CCHS + pt[k] * CPITCH + (pc4[k] << 2) + 1];
        p[0] = pf[k].x; p[1] = pf[k].y; p[2] = pf[k].z; p[3] = pf[k].w;
      }
    if (cc + 8 < 256) {
      #pragma unroll
      for (int k = 0; k < 5; ++k) {
        const int g = h16 - 1 + pt[k];
        if (pok[k]) pf[k] = feat4[((cc + 8 + pch[k]) << 8) + (g << 3) + pc4[k]];
      }
    }
    __syncthreads();
    #pragma unroll
    for (int cl = 0; cl < 8; ++cl) {
      const float* wAp = w + co0 * 2304 + (cc + cl) * 9;
      const float* wBp = wAp + 2304;
      double wa[9], wb[9];
      #pragma unroll
      for (int q = 0; q < 9; ++q) { wa[q] = (double)wAp[q]; wb[q] = (double)wBp[q]; }
      const float* ir = &il[buf][cl * CCHS + yl * CPITCH + x0];
      #pragma unroll
      for (int ky = 0; ky < 3; ++ky) {
        const float2 q0 = *(const float2*)(ir + ky * CPITCH);
        const float2 q1 = *(const float2*)(ir + ky * CPITCH + 2);
        const double v0 = (double)q0.x, v1 = (double)q0.y;
        const double v2 = (double)q1.x, v3 = (double)q1.y;
        aA0 += v0 * wa[3*ky+0] + v1 * wa[3*ky+1] + v2 * wa[3*ky+2];
        aA1 += v1 * wa[3*ky+0] + v2 * wa[3*ky+1] + v3 * wa[3*ky+2];
        aB0 += v0 * wb[3*ky+0] + v1 * wb[3*ky+1] + v2 * wb[3*ky+2];
        aB1 += v1 * wb[3*ky+0] + v2 * wb[3*ky+1] + v3 * wb[3*ky+2];
      }
    }
  }
  const double bA = (double)bias[co0], bB = (double)bias[co0 + 1];
  const int y = h16 + yl;
  float2 rA, rB;
  rA.x = (float)fmax(aA0 + bA, 0.0); rA.y = (float)fmax(aA1 + bA, 0.0);
  rB.x = (float)fmax(aB0 + bB, 0.0); rB.y = (float)fmax(aB1 + bB, 0.0);
  *(float2*)&xout[(co0 << 10) + (y << 5) + x0] = rA;
  *(float2*)&xout[((co0 + 1) << 10) + (y << 5) + x0] = rB;
}

// ================= 1x1 heads — R11 split-K, 1024 thr ========================
// Old: 216 blocks x 256 thr = 0.84 waves/SIMD, 512-deep serial L2-load chain
// per thread -> latency-bound, hidden under sweep in top-5 since R3.
// New: same 216 blocks, 1024 thr: 4 thr/px, each sums 128 channels (fp64),
// LDS-reduce, kq=0 applies bias+sigmoid. Waves 864 -> 3456 (3.4/SIMD),
// chain 512 -> 128 loads. fp64 reassociation only.
__global__ __launch_bounds__(1024) void head1x1_k(
    const float* __restrict__ x,
    const float* __restrict__ cls_w, const float* __restrict__ cls_b,
    const float* __restrict__ bbox_w, const float* __restrict__ bbox_b,
    float* __restrict__ out, float* __restrict__ bbox_out)
{
  __shared__ float wl[512];
  __shared__ double red[3][256];
  const int bid = blockIdx.x;
  const int co = bid >> 2;                     // 0..53
  const int tid = threadIdx.x;
  const int kq = tid >> 8;                     // K-quarter 0..3
  const int p  = tid & 255;
  const int px = ((bid & 3) << 8) | p;
  const bool is_cls = co < 18;
  const float* wsrc = is_cls ? (cls_w + co * 512) : (bbox_w + (co - 18) * 512);
  if (tid < 512) wl[tid] = wsrc[tid];
  __syncthreads();
  const int c0 = kq << 7;
  double a0 = 0.0, a1 = 0.0, a2 = 0.0, a3 = 0.0;
  #pragma unroll 8
  for (int c = c0; c < c0 + 128; c += 4) {
    a0 += (double)x[((c + 0) << 10) | px] * (double)wl[c + 0];
    a1 += (double)x[((c + 1) << 10) | px] * (double)wl[c + 1];
    a2 += (double)x[((c + 2) << 10) | px] * (double)wl[c + 2];
    a3 += (double)x[((c + 3) << 10) | px] * (double)wl[c + 3];
  }
  const double part = (a0 + a1) + (a2 + a3);
  if (kq) red[kq - 1][p] = part;
  __syncthreads();
  if (kq == 0) {
    const double acc = ((part + red[0][p]) + (red[1][p] + red[2][p])) +
                       (double)(is_cls ? cls_b[co] : bbox_b[co - 18]);
    if (is_cls)
      out[36864 + (co << 10) + px] = (float)(1.0 / (1.0 + exp(-acc)));
    else
      bbox_out[((co - 18) << 10) + px] = (float)acc;
  }
}

// ============ anchors + box decode + clip + key build =======================
__global__ __launch_bounds__(256) void proposals_k(
    const float* __restrict__ bbox, const int* __restrict__ imgsz,
    const float* __restrict__ out, float* __restrict__ props,
    u64* __restrict__ keys, unsigned* __restrict__ rank)
{
  const int r = blockIdx.x * 256 + threadIdx.x;
  if (r >= 9216) return;
  const float4 d = ((const float4*)bbox)[r];
  const int cell = r / 9, a = r - cell * 9;
  const int ix = cell & 31, iy = cell >> 5;
  const int ri = a / 3, si = a - ri * 3;
  const double ratio = (ri == 0) ? 0.5 : (ri == 1 ? 1.0 : 2.0);
  const double scale = (si == 0) ? 128.0 : (si == 1 ? 256.0 : 512.0);
  const double hr = sqrt(ratio), wr = 1.0 / hr;
  const double bx = nearbyint(wr * scale * 0.5);
  const double by = nearbyint(hr * scale * 0.5);
  const double cx = ix * 16.0, cy = iy * 16.0;
  const double w = 2.0 * bx, hh = 2.0 * by;
  const double pcx = (double)d.x * w + cx;
  const double pcy = (double)d.y * hh + cy;
  const double pw = exp((double)d.z) * w;
  const double ph = exp((double)d.w) * hh;
  const double im = (double)imgsz[0];
  float4 o;
  o.x = (float)fmin(fmax(pcx - 0.5 * pw, 0.0), im);
  o.y = (float)fmin(fmax(pcy - 0.5 * ph, 0.0), im);
  o.z = (float)fmin(fmax(pcx + 0.5 * pw, 0.0), im);
  o.w = (float)fmin(fmax(pcy + 0.5 * ph, 0.0), im);
  ((float4*)props)[r] = o;
  const float s = out[36864 + ((2 * (r >> 10) + 1) << 10) + (r & 1023)];
  keys[r] = ((u64)__float_as_uint(s) << 32) | (unsigned)(0x7FFFFFFF - r);
  rank[r] = 0u;
}

// ================= rank sort ================================================
__global__ __launch_bounds__(256) void rank_k(
    const u64* __restrict__ keys, unsigned* __restrict__ rank)
{
  const int jt = blockIdx.x % 36, ic = blockIdx.x / 36;
  const int j = jt * 256 + threadIdx.x;
  const u64 kj = keys[j];
  const int lane = threadIdx.x & 63;
  const int base = ic * 576;
  unsigned lo[9], hi[9];
  #pragma unroll
  for (int rr = 0; rr < 9; ++rr) {
    const u64 k = keys[base + rr * 64 + lane];
    lo[rr] = (unsigned)k; hi[rr] = (unsigned)(k >> 32);
  }
  unsigned cnt = 0;
  #pragma unroll
  for (int rr = 0; rr < 9; ++rr) {
    #pragma unroll
    for (int l = 0; l < 64; ++l) {
      const unsigned llo = (unsigned)__builtin_amdgcn_readlane((int)lo[rr], l);
      const unsigned lhi = (unsigned)__builtin_amdgcn_readlane((int)hi[rr], l);
      const u64 ki = ((u64)lhi << 32) | llo;
      cnt += (ki > kj) ? 1u : 0u;
    }
  }
  atomicAdd(&rank[j], cnt);
}

// ================= scatter into sorted order ================================
__global__ __launch_bounds__(256) void scatter_k(
    const u64* __restrict__ keys, const unsigned* __restrict__ rank,
    const float* __restrict__ props, u64* __restrict__ skeys,
    float4* __restrict__ sboxes)
{
  const int r = blockIdx.x * 256 + threadIdx.x;
  if (r >= 9216) return;
  const unsigned rk = rank[r];
  skeys[rk] = keys[r];
  sboxes[rk] = ((const float4*)props)[r];
}

// ====== suppression bitmask (chunk 64, LDS boxes) ===========================
__global__ __launch_bounds__(256) void mask_k(
    const float4* __restrict__ sb4, u64* __restrict__ mask)
{
  __shared__ __align__(16) float4 ib[64];
  const int ci = blockIdx.x;                  // 0..143
  const int Wb = blockIdx.y << 2;
  const int i_lo = ci << 6;
  const int i_hi = min(i_lo + 64, (Wb + 4) << 6);
  if (i_lo >= i_hi) return;                   // uniform across block
  const int wv = threadIdx.x >> 6, lane = threadIdx.x & 63;
  const int W = Wb + wv;
  const int cnt = i_hi - i_lo;
  if (threadIdx.x < cnt) ib[threadIdx.x] = sb4[i_lo + threadIdx.x];
  __syncthreads();
  const float4 bj = sb4[(W << 6) + lane];
  const float areaJ = (bj.z - bj.x) * (bj.w - bj.y);
  const int n = i_hi - i_lo;
  #pragma unroll 8
  for (int k = 0; k < n; ++k) {
    const float4 bi = ib[k];
    const float areaI = (bi.z - bi.x) * (bi.w - bi.y);
    const float ix1 = fmaxf(bj.x, bi.x), iy1 = fmaxf(bj.y, bi.y);
    const float ix2 = fminf(bj.z, bi.z), iy2 = fminf(bj.w, bi.w);
    const float iw = fmaxf(ix2 - ix1, 0.0f), ih = fmaxf(iy2 - iy1, 0.0f);
    const double inter = (double)iw * (double)ih;
    const double uni = (double)areaJ + (double)areaI - inter + 1e-9;
    const bool pred = inter > 0.3 * uni;
    const u64 bal = __ballot(pred);
    const int i = i_lo + k;
    if (lane == 0) mask[(size_t)i * 144 + W] = bal;
  }
}

// ====== sweep v8: one barrier per sg; delta-pull fused into wave0 ===========
__global__ __launch_bounds__(1024) void sweep_out_k(
    const u64* __restrict__ mask, const u64* __restrict__ skeys,
    const float4* __restrict__ sboxes, float* __restrict__ out)
{
  extern __shared__ __align__(16) char sm[];
  u64* subm   = (u64*)sm;                        // 2*4608 u64 = 73,728 B
  u64* supS   = subm + 9216;                     // 2*8 u64    = 128 B
  u64* keptS  = supS + 16;                       // 144 u64    = 1,152 B
  unsigned short* kpl = (unsigned short*)(keptS + 144);  // 9216 u16 = 18,432 B
  int* kcnt  = (int*)(kpl + 9216);               // 4 B   (total 93,444)

  const int tid = threadIdx.x;
  const int lane = tid & 63, wv = tid >> 6;
  if (tid == 0) *kcnt = 0;
  if (tid < 144) keptS[tid] = 0ULL;
  if (tid < 16) supS[tid] = 0ULL;
  // stage sg 0 into buffer 0 (rows 0..511, words 0..7, stride 9)
  if (tid < 512) {
    const int wq = tid & 7, r0 = tid >> 3;
    #pragma unroll
    for (int k = 0; k < 8; ++k) {
      const int i = r0 + (k << 6);
      subm[i * 9 + wq] = mask[(size_t)i * 144 + wq];
    }
  }
  __syncthreads();

  int Kpp = 0, Kp = 0;                           // wave0-only registers

  for (int sg = 0; sg < 18; ++sg) {
    const int buf = sg & 1, nb = buf ^ 1;
    const int wbase = sg << 3;
    const int ibase = wbase << 6;
    if (wv == 0) {
      // ---- delta-pull: rows [Kpp,Kp) x words(sg), no barrier needed ----
      u64 dacc = 0ULL;
      {
        const int wq = lane & 7;
        int j = Kpp + (lane >> 3);
        for (; j + 24 < Kp; j += 32) {
          const u64 a0 = mask[(size_t)kpl[j +  0] * 144 + wbase + wq];
          const u64 a1 = mask[(size_t)kpl[j +  8] * 144 + wbase + wq];
          const u64 a2 = mask[(size_t)kpl[j + 16] * 144 + wbase + wq];
          const u64 a3 = mask[(size_t)kpl[j + 24] * 144 + wbase + wq];
          dacc |= (a0 | a1) | (a2 | a3);
        }
        for (; j < Kp; j += 8)
          dacc |= mask[(size_t)kpl[j] * 144 + wbase + wq];
      }
      dacc |= __shfl_xor(dacc, 8, 64);
      dacc |= __shfl_xor(dacc, 16, 64);
      dacc |= __shfl_xor(dacc, 32, 64);          // lane l: OR for word l&7
      u64 myAlive = (lane < 8) ? ~(supS[(buf << 3) + lane] | dacc) : 0ULL;
      if (lane < 8) supS[(buf << 3) + lane] = 0ULL;  // ready for sg+2 pre-pull
      const u64* sub = subm + buf * 4608;
      // preload all 8 diagonal rowL words (independent ds_reads)
      u64 rowL8[8];
      #pragma unroll
      for (int w = 0; w < 8; ++w)
        rowL8[w] = sub[((w << 6) + lane) * 9 + w];
      int Kcur = Kp;
      #pragma unroll
      for (int w = 0; w < 8; ++w) {
        const u64 av = __shfl(myAlive, w, 64);
        if (av == 0ULL) continue;
        const u64 rowL = rowL8[w];
        u64 cand = av, keptw = 0ULL;
        while (cand) {
          const int b = (int)__builtin_ctzll(cand);   // uniform
          keptw |= 1ULL << b;
          const u64 sup =
              ((u64)(unsigned)__builtin_amdgcn_readlane((int)(rowL >> 32), b)
               << 32) |
              (unsigned)__builtin_amdgcn_readlane((int)rowL, b);
          cand &= ~(sup | (1ULL << b));
        }
        if (lane == 0) keptS[wbase + w] = keptw;
        if (keptw) {
          if ((keptw >> lane) & 1ULL) {
            const int pre =
                __builtin_popcountll(keptw & ((1ULL << lane) - 1ULL));
            kpl[Kcur + pre] = (unsigned short)(ibase + (w << 6) + lane);
          }
          Kcur += __builtin_popcountll(keptw);
          // apply kept rows to later words of this sg (batch 8 per round)
          u64 t = keptw;
          while (t) {
            int bs[8]; int nn = 0;
            #pragma unroll
            for (int s = 0; s < 8; ++s) {
              if (t) { bs[s] = (int)__builtin_ctzll(t); t &= t - 1ULL; nn = s + 1; }
              else bs[s] = 0;
            }
            const int kk = lane >> 3, wq = lane & 7;
            u64 r = (kk < nn) ? sub[((w << 6) + bs[kk]) * 9 + wq] : 0ULL;
            r |= __shfl_down(r, 8, 64);
            r |= __shfl_down(r, 16, 64);
            r |= __shfl_down(r, 32, 64);
            myAlive &= ~r;                       // lanes 0..7 hold the OR
          }
        }
      }
      Kpp = Kp; Kp = Kcur;
      if (lane == 0) *kcnt = Kcur;               // publish once, pre-barrier
    } else if (wv < 12) {                        // pre-pull(sg+1): rows [0,Kh)
      if (sg + 1 < 18) {
        const int Kh = *kcnt;                    // either old or new K: benign
        const int t6 = tid - 64;                 // 0..703
        const int wq = t6 & 7, str = t6 >> 3;    // 88 streams x 8 words
        const int wb2 = (sg + 1) << 3;
        u64 acc = 0ULL;
        int j = str;
        for (; j + 3 * 88 < Kh; j += 4 * 88) {
          const u64 a0 = mask[(size_t)kpl[j + 0 * 88] * 144 + wb2 + wq];
          const u64 a1 = mask[(size_t)kpl[j + 1 * 88] * 144 + wb2 + wq];
          const u64 a2 = mask[(size_t)kpl[j + 2 * 88] * 144 + wb2 + wq];
          const u64 a3 = mask[(size_t)kpl[j + 3 * 88] * 144 + wb2 + wq];
          acc |= (a0 | a1) | (a2 | a3);
        }
        for (; j < Kh; j += 88)
          acc |= mask[(size_t)kpl[j] * 144 + wb2 + wq];
        if (acc) {
          atomicOr((unsigned*)&supS[(nb << 3) + wq], (unsigned)acc);
          atomicOr(((unsigned*)&supS[(nb << 3) + wq]) + 1, (unsigned)(acc >> 32));
        }
      }
    } else if (sg + 1 < 18) {                    // stage(sg+1) into subm[nb]
      const int s = tid - 768;                   // 0..255
      const int wq = s & 7, r0 = s >> 3;         // 32 rows x 16 iters
      const int ib2 = (sg + 1) << 9;
      const int wb2 = (sg + 1) << 3;
      #pragma unroll
      for (int k = 0; k < 16; ++k) {
        const int i = r0 + (k << 5);
        subm[nb * 4608 + i * 9 + wq] = mask[(size_t)(ib2 + i) * 144 + wb2 + wq];
      }
    }
    __syncthreads();                             // orders everything per sg
  }
  for (int i = tid; i < 9216; i += 1024) {
    const u64 key = skeys[i];
    const int orig = 0x7FFFFFFF - (int)(unsigned)(key & 0xFFFFFFFFULL);
    const bool kp = (keptS[i >> 6] >> (i & 63)) & 1ULL;
    float4 ob = sboxes[i];
    if (!kp) { ob.x = 0.f; ob.y = 0.f; ob.z = 0.f; ob.w = 0.f; }
    ((float4*)out)[orig] = ob;
    out[55296 + orig] = kp ? 1.0f : 0.0f;
  }
}

// ================= fallback NMS (small ws) ==================================
__global__ __launch_bounds__(1024) void nms_fallback_k(
    const float* __restrict__ props, float* __restrict__ out)
{
  __shared__ u64 wmax[16];
  __shared__ float4 curBoxS;
  const int tid = threadIdx.x, wid = tid >> 6, lane = tid & 63;
  u64 key[9];
  float4 box[9];
  #pragma unroll
  for (int j = 0; j < 9; ++j) {
    const int r = tid + (j << 10);
    box[j] = ((const float4*)props)[r];
    const float s = out[36864 + ((2 * (r >> 10) + 1) << 10) + (r & 1023)];
    key[j] = ((u64)__float_as_uint(s) << 32) | (unsigned)(0x7FFFFFFF - r);
  }
  unsigned kept = 0;
  for (;;) {
    u64 m = key[0];
    #pragma unroll
    for (int j = 1; j < 9; ++j) m = key[j] > m ? key[j] : m;
    #pragma unroll
    for (int off = 32; off; off >>= 1) {
      const u64 o = __shfl_down(m, off, 64);
      if (o > m) m = o;
    }
    if (lane == 0) wmax[wid] = m;
    __syncthreads();
    u64 K = wmax[0];
    #pragma unroll
    for (int wv2 = 1; wv2 < 16; ++wv2) { const u64 t = wmax[wv2]; if (t > K) K = t; }
    if (K == 0) break;
    #pragma unroll
    for (int j = 0; j < 9; ++j)
      if (key[j] == K) { curBoxS = box[j]; key[j] = 0; kept |= 1u << j; }
    __syncthreads();
    const float4 cb = curBoxS;
    const float areaC = (cb.z - cb.x) * (cb.w - cb.y);
    #pragma unroll
    for (int j = 0; j < 9; ++j) {
      if (key[j]) {
        const float4 b = box[j];
        const float ix1 = fmaxf(b.x, cb.x), iy1 = fmaxf(b.y, cb.y);
        const float ix2 = fminf(b.z, cb.z), iy2 = fminf(b.w, cb.w);
        const float iw = fmaxf(ix2 - ix1, 0.0f), ih = fmaxf(iy2 - iy1, 0.0f);
        const float areaB = (b.z - b.x) * (b.w - b.y);
        const double inter = (double)iw * (double)ih;
        const double uni = (double)areaB + (double)areaC - inter + 1e-9;
        if (inter > 0.3 * uni) key[j] = 0;
      }
    }
    __syncthreads();
  }
  #pragma unroll
  for (int j = 0; j < 9; ++j) {
    const int r = tid + (j << 10);
    const bool kp = (kept >> j) & 1u;
    float4 ob = box[j];
    if (!kp) { ob.x = 0.f; ob.y = 0.f; ob.z = 0.f; ob.w = 0.f; }
    ((float4*)out)[r] = ob;
    out[55296 + r] = kp ? 1.0f : 0.0f;
  }
}

// ============================================================================
extern "C" void kernel_launch(void* const* d_in, const int* in_sizes, int n_in,
                              void* d_out, int out_size, void* d_ws, size_t ws_size,
                              hipStream_t stream)
{
  const float* feat   = (const float*)d_in[0];
  const int*   imgsz  = (const int*)d_in[1];
  const float* conv_w = (const float*)d_in[2];
  const float* conv_b = (const float*)d_in[3];
  const float* cls_w  = (const float*)d_in[4];
  const float* cls_b  = (const float*)d_in[5];
  const float* bbox_w = (const float*)d_in[6];
  const float* bbox_b = (const float*)d_in[7];
  float* out = (float*)d_out;
  char*  ws  = (char*)d_ws;
  float* x      = (float*)(ws + X_B);
  float* bbox   = (float*)(ws + BBOX_B);
  float* props  = (float*)(ws + PROPS_B);
  u64*      keys  = (u64*)(ws + KEYS_B);
  unsigned* rankp = (unsigned*)(ws + RANK_B);
  u64*      skeys = (u64*)(ws + SKEYS_B);
  float4*   sboxs = (float4*)(ws + SBOX_B);
  u64*      maskp = (u64*)(ws + MASK_B);

  if (ws_size >= (size_t)WS_NEED) {
    hipLaunchKernelGGL(conv3x3_mfma_k, dim3(512), dim3(256), 0, stream,
                       feat, conv_w, conv_b, x);
    hipLaunchKernelGGL(head1x1_k, dim3(216), dim3(1024), 0, stream,
                       x, cls_w, cls_b, bbox_w, bbox_b, out, bbox);
    hipLaunchKernelGGL(proposals_k, dim3(36), dim3(256), 0, stream,
                       bbox, imgsz, out, props, keys, rankp);
    hipLaunchKernelGGL(rank_k, dim3(576), dim3(256), 0, stream, keys, rankp);
    hipLaunchKernelGGL(scatter_k, dim3(36), dim3(256), 0, stream,
                       keys, rankp, props, skeys, sboxs);
    hipLaunchKernelGGL(mask_k, dim3(144, 36), dim3(256), 0, stream,
                       sboxs, maskp);
    hipLaunchKernelGGL(sweep_out_k, dim3(1), dim3(1024), 93444, stream,
                       maskp, skeys, sboxs, out);
  } else {
    hipLaunchKernelGGL(conv3x3_relu_fb_k, dim3(512), dim3(256), 0, stream,
                       feat, conv_w, conv_b, x);
    hipLaunchKernelGGL(head1x1_k, dim3(216), dim3(1024), 0, stream,
                       x, cls_w, cls_b, bbox_w, bbox_b, out, bbox);
    hipLaunchKernelGGL(proposals_k, dim3(36), dim3(256), 0, stream,
                       bbox, imgsz, out, props, keys, rankp);
    hipLaunchKernelGGL(nms_fallback_k, dim3(1), dim3(1024), 0, stream,
                       props, out);
  }
}

// Round 12
// 239.441 us; speedup vs baseline: 1.1113x; 1.0146x over previous
//
#include <hip/hip_runtime.h>
#include <math.h>

// ---------------- workspace layout (bytes) ----------------
#define X_B      0         // 512*1024 f32   = 2,097,152
#define BBOX_B   2097152   // 36*1024 f32    = 147,456
#define PROPS_B  2244608   // 9216 float4    = 147,456
#define KEYS_B   2392064   // 9216 u64       = 73,728
#define RANK_B   2465792   // 9216 u32       = 36,864
#define SKEYS_B  2502656   // 9216 u64       = 73,728
#define SBOX_B   2576384   // 9216 float4    = 147,456
#define MASK_B   2725888   // 9216*144 u64   = 10,616,832 (end 13,342,720)
#define WS_NEED  13400000

typedef unsigned long long u64;
typedef double v4d __attribute__((ext_vector_type(4)));

// ================= conv 3x3 (256->512, 32x32, pad 1) + ReLU =================
// R8/R6 conv (best verified). Raw-pitch-580 weight staging (conflict-free
// b128), pitch-137 features, XCD-aware remap, 4 indep MFMA chains.
// D layout (probe-verified): row = (lane>>4)+4*reg, col = lane&15.
__global__ __launch_bounds__(256, 2) void conv3x3_mfma_k(
    const float* __restrict__ feat, const float* __restrict__ w,
    const float* __restrict__ bias, float* __restrict__ xout)
{
  __shared__ float wl[9280];   // [co][580 pitch] raw chunk weights  37,120 B
  __shared__ float fl[8768];   // [ci][137 pitch]: 4 rows x 34 + pad 35,072 B

  const int tid = threadIdx.x;
  const int bid = blockIdx.x;
  const int ct = ((bid & 7) << 2) | ((bid >> 3) >> 4);   // co-tile 0..31
  const int g  = (bid >> 3) & 15;                        // px-group 0..15
  const int co0 = ct << 4;
  const int y0  = g << 1;

  for (int i = tid; i < 8768; i += 256) fl[i] = 0.0f;

  const int lane = tid & 63, wv = tid >> 6;
  const int q = lane >> 4, n = lane & 15;
  const int wy = wv >> 1, xb = (wv & 1) << 4;
  const int xn = xb + n;

  v4d ac0 = {0.0, 0.0, 0.0, 0.0}, ac1 = {0.0, 0.0, 0.0, 0.0};
  v4d ac2 = {0.0, 0.0, 0.0, 0.0}, ac3 = {0.0, 0.0, 0.0, 0.0};
  const float4* feat4 = (const float4*)feat;

  __syncthreads();

  for (int c = 0; c < 4; ++c) {
    const int cb = c << 6;
    #pragma unroll
    for (int i = 0; i < 9; ++i) {
      const int idx4 = tid + (i << 8);
      const int co = idx4 / 144;
      const int s4 = idx4 - co * 144;
      *(float4*)&wl[co * 580 + (s4 << 2)] =
          *(const float4*)(w + (co0 + co) * 2304 + c * 576 + (s4 << 2));
    }
    #pragma unroll
    for (int i = 0; i < 8; ++i) {
      const int idx4 = tid + (i << 8);
      const int ci = idx4 >> 5;
      const int rr = (idx4 >> 3) & 3;
      const int x4 = idx4 & 7;
      const int grow = y0 - 1 + rr;
      if ((unsigned)grow < 32u) {
        const float4 v = feat4[((cb + ci) << 8) + (grow << 3) + x4];
        float* p = &fl[ci * 137 + rr * 34 + 1 + (x4 << 2)];
        p[0] = v.x; p[1] = v.y; p[2] = v.z; p[3] = v.w;
      }
    }
    __syncthreads();
    #pragma unroll
    for (int tap = 0; tap < 9; ++tap) {
      const int ky = tap / 3, kx = tap - 3 * (tap / 3);
      const float* ab = &wl[n * 580 + q * 9 + tap];                // + u*36
      const float* bb = &fl[q * 137 + (wy + ky) * 34 + xn + kx];   // + u*548
      #pragma unroll
      for (int u = 0; u < 16; u += 4) {
        ac0 = __builtin_amdgcn_mfma_f64_16x16x4f64(
            (double)ab[(u + 0) * 36], (double)bb[(u + 0) * 548], ac0, 0, 0, 0);
        ac1 = __builtin_amdgcn_mfma_f64_16x16x4f64(
            (double)ab[(u + 1) * 36], (double)bb[(u + 1) * 548], ac1, 0, 0, 0);
        ac2 = __builtin_amdgcn_mfma_f64_16x16x4f64(
            (double)ab[(u + 2) * 36], (double)bb[(u + 2) * 548], ac2, 0, 0, 0);
        ac3 = __builtin_amdgcn_mfma_f64_16x16x4f64(
            (double)ab[(u + 3) * 36], (double)bb[(u + 3) * 548], ac3, 0, 0, 0);
      }
    }
    __syncthreads();
  }

  const int pbase = (g << 6) + (wv << 4) + n;
  #pragma unroll
  for (int i = 0; i < 4; ++i) {
    const int co = co0 + q + (i << 2);
    const double s = (ac0[i] + ac1[i]) + (ac2[i] + ac3[i]);
    const double v = fmax(s + (double)bias[co], 0.0);
    xout[(co << 10) + pbase] = (float)v;
  }
}

// ========== fallback conv (small ws) ========================================
#define CPITCH 38
#define CCHS   (18 * CPITCH)
__global__ __launch_bounds__(256) void conv3x3_relu_fb_k(
    const float* __restrict__ feat, const float* __restrict__ w,
    const float* __restrict__ bias, float* __restrict__ xout)
{
  __shared__ float il[2][8 * CCHS];
  const int cp = blockIdx.x >> 1, h = blockIdx.x & 1;
  const int tid = threadIdx.x;
  const int h16 = h << 4;
  const int co0 = cp << 1;
  for (int i = tid; i < 8 * CCHS; i += 256) { il[0][i] = 0.0f; il[1][i] = 0.0f; }
  const int yl = tid >> 4;
  const int x0 = (tid & 15) << 1;
  double aA0 = 0.0, aA1 = 0.0, aB0 = 0.0, aB1 = 0.0;
  const float4* feat4 = (const float4*)feat;
  float4 pf[5]; int pch[5], pt[5], pc4[5], pok[5];
  #pragma unroll
  for (int k = 0; k < 5; ++k) {
    const int i = tid + (k << 8);
    const int ch = i / 144, rem = i - ch * 144;
    const int t = rem >> 3, c4 = rem & 7;
    const int g = h16 - 1 + t;
    pch[k] = ch; pt[k] = t; pc4[k] = c4;
    pok[k] = (i < 1152) && ((unsigned)g < 32u);
    pf[k] = pok[k] ? feat4[(ch << 8) + (g << 3) + c4] : float4{0.f,0.f,0.f,0.f};
  }
  __syncthreads();
  for (int cc = 0; cc < 256; cc += 8) {
    const int buf = (cc >> 3) & 1;
    #pragma unroll
    for (int k = 0; k < 5; ++k)
      if (pok[k]) {
        float* p = &il[buf][pch[k] * CCHS + pt[k] * CPITCH + (pc4[k] << 2) + 1];
        p[0] = pf[k].x; p[1] = pf[k].y; p[2] = pf[k].z; p[3] = pf[k].w;
      }
    if (cc + 8 < 256) {
      #pragma unroll
      for (int k = 0; k < 5; ++k) {
        const int g = h16 - 1 + pt[k];
        if (pok[k]) pf[k] = feat4[((cc + 8 + pch[k]) << 8) + (g << 3) + pc4[k]];
      }
    }
    __syncthreads();
    #pragma unroll
    for (int cl = 0; cl < 8; ++cl) {
      const float* wAp = w + co0 * 2304 + (cc + cl) * 9;
      const float* wBp = wAp + 2304;
      double wa[9], wb[9];
      #pragma unroll
      for (int q = 0; q < 9; ++q) { wa[q] = (double)wAp[q]; wb[q] = (double)wBp[q]; }
      const float* ir = &il[buf][cl * CCHS + yl * CPITCH + x0];
      #pragma unroll
      for (int ky = 0; ky < 3; ++ky) {
        const float2 q0 = *(const float2*)(ir + ky * CPITCH);
        const float2 q1 = *(const float2*)(ir + ky * CPITCH + 2);
        const double v0 = (double)q0.x, v1 = (double)q0.y;
        const double v2 = (double)q1.x, v3 = (double)q1.y;
        aA0 += v0 * wa[3*ky+0] + v1 * wa[3*ky+1] + v2 * wa[3*ky+2];
        aA1 += v1 * wa[3*ky+0] + v2 * wa[3*ky+1] + v3 * wa[3*ky+2];
        aB0 += v0 * wb[3*ky+0] + v1 * wb[3*ky+1] + v2 * wb[3*ky+2];
        aB1 += v1 * wb[3*ky+0] + v2 * wb[3*ky+1] + v3 * wb[3*ky+2];
      }
    }
  }
  const double bA = (double)bias[co0], bB = (double)bias[co0 + 1];
  const int y = h16 + yl;
  float2 rA, rB;
  rA.x = (float)fmax(aA0 + bA, 0.0); rA.y = (float)fmax(aA1 + bA, 0.0);
  rB.x = (float)fmax(aB0 + bB, 0.0); rB.y = (float)fmax(aB1 + bB, 0.0);
  *(float2*)&xout[(co0 << 10) + (y << 5) + x0] = rA;
  *(float2*)&xout[((co0 + 1) << 10) + (y << 5) + x0] = rB;
}

// ================= 1x1 heads — split-K, 1024 thr (R11, kept) ================
__global__ __launch_bounds__(1024) void head1x1_k(
    const float* __restrict__ x,
    const float* __restrict__ cls_w, const float* __restrict__ cls_b,
    const float* __restrict__ bbox_w, const float* __restrict__ bbox_b,
    float* __restrict__ out, float* __restrict__ bbox_out)
{
  __shared__ float wl[512];
  __shared__ double red[3][256];
  const int bid = blockIdx.x;
  const int co = bid >> 2;                     // 0..53
  const int tid = threadIdx.x;
  const int kq = tid >> 8;                     // K-quarter 0..3
  const int p  = tid & 255;
  const int px = ((bid & 3) << 8) | p;
  const bool is_cls = co < 18;
  const float* wsrc = is_cls ? (cls_w + co * 512) : (bbox_w + (co - 18) * 512);
  if (tid < 512) wl[tid] = wsrc[tid];
  __syncthreads();
  const int c0 = kq << 7;
  double a0 = 0.0, a1 = 0.0, a2 = 0.0, a3 = 0.0;
  #pragma unroll 8
  for (int c = c0; c < c0 + 128; c += 4) {
    a0 += (double)x[((c + 0) << 10) | px] * (double)wl[c + 0];
    a1 += (double)x[((c + 1) << 10) | px] * (double)wl[c + 1];
    a2 += (double)x[((c + 2) << 10) | px] * (double)wl[c + 2];
    a3 += (double)x[((c + 3) << 10) | px] * (double)wl[c + 3];
  }
  const double part = (a0 + a1) + (a2 + a3);
  if (kq) red[kq - 1][p] = part;
  __syncthreads();
  if (kq == 0) {
    const double acc = ((part + red[0][p]) + (red[1][p] + red[2][p])) +
                       (double)(is_cls ? cls_b[co] : bbox_b[co - 18]);
    if (is_cls)
      out[36864 + (co << 10) + px] = (float)(1.0 / (1.0 + exp(-acc)));
    else
      bbox_out[((co - 18) << 10) + px] = (float)acc;
  }
}

// ============ anchors + box decode + clip + key build =======================
__global__ __launch_bounds__(256) void proposals_k(
    const float* __restrict__ bbox, const int* __restrict__ imgsz,
    const float* __restrict__ out, float* __restrict__ props,
    u64* __restrict__ keys, unsigned* __restrict__ rank)
{
  const int r = blockIdx.x * 256 + threadIdx.x;
  if (r >= 9216) return;
  const float4 d = ((const float4*)bbox)[r];
  const int cell = r / 9, a = r - cell * 9;
  const int ix = cell & 31, iy = cell >> 5;
  const int ri = a / 3, si = a - ri * 3;
  const double ratio = (ri == 0) ? 0.5 : (ri == 1 ? 1.0 : 2.0);
  const double scale = (si == 0) ? 128.0 : (si == 1 ? 256.0 : 512.0);
  const double hr = sqrt(ratio), wr = 1.0 / hr;
  const double bx = nearbyint(wr * scale * 0.5);
  const double by = nearbyint(hr * scale * 0.5);
  const double cx = ix * 16.0, cy = iy * 16.0;
  const double w = 2.0 * bx, hh = 2.0 * by;
  const double pcx = (double)d.x * w + cx;
  const double pcy = (double)d.y * hh + cy;
  const double pw = exp((double)d.z) * w;
  const double ph = exp((double)d.w) * hh;
  const double im = (double)imgsz[0];
  float4 o;
  o.x = (float)fmin(fmax(pcx - 0.5 * pw, 0.0), im);
  o.y = (float)fmin(fmax(pcy - 0.5 * ph, 0.0), im);
  o.z = (float)fmin(fmax(pcx + 0.5 * pw, 0.0), im);
  o.w = (float)fmin(fmax(pcy + 0.5 * ph, 0.0), im);
  ((float4*)props)[r] = o;
  const float s = out[36864 + ((2 * (r >> 10) + 1) << 10) + (r & 1023)];
  keys[r] = ((u64)__float_as_uint(s) << 32) | (unsigned)(0x7FFFFFFF - r);
  rank[r] = 0u;
}

// ================= rank sort ================================================
__global__ __launch_bounds__(256) void rank_k(
    const u64* __restrict__ keys, unsigned* __restrict__ rank)
{
  const int jt = blockIdx.x % 36, ic = blockIdx.x / 36;
  const int j = jt * 256 + threadIdx.x;
  const u64 kj = keys[j];
  const int lane = threadIdx.x & 63;
  const int base = ic * 576;
  unsigned lo[9], hi[9];
  #pragma unroll
  for (int rr = 0; rr < 9; ++rr) {
    const u64 k = keys[base + rr * 64 + lane];
    lo[rr] = (unsigned)k; hi[rr] = (unsigned)(k >> 32);
  }
  unsigned cnt = 0;
  #pragma unroll
  for (int rr = 0; rr < 9; ++rr) {
    #pragma unroll
    for (int l = 0; l < 64; ++l) {
      const unsigned llo = (unsigned)__builtin_amdgcn_readlane((int)lo[rr], l);
      const unsigned lhi = (unsigned)__builtin_amdgcn_readlane((int)hi[rr], l);
      const u64 ki = ((u64)lhi << 32) | llo;
      cnt += (ki > kj) ? 1u : 0u;
    }
  }
  atomicAdd(&rank[j], cnt);
}

// ================= scatter into sorted order ================================
__global__ __launch_bounds__(256) void scatter_k(
    const u64* __restrict__ keys, const unsigned* __restrict__ rank,
    const float* __restrict__ props, u64* __restrict__ skeys,
    float4* __restrict__ sboxes)
{
  const int r = blockIdx.x * 256 + threadIdx.x;
  if (r >= 9216) return;
  const unsigned rk = rank[r];
  skeys[rk] = keys[r];
  sboxes[rk] = ((const float4*)props)[r];
}

// ====== suppression bitmask (chunk 64, LDS boxes) ===========================
__global__ __launch_bounds__(256) void mask_k(
    const float4* __restrict__ sb4, u64* __restrict__ mask)
{
  __shared__ __align__(16) float4 ib[64];
  const int ci = blockIdx.x;                  // 0..143
  const int Wb = blockIdx.y << 2;
  const int i_lo = ci << 6;
  const int i_hi = min(i_lo + 64, (Wb + 4) << 6);
  if (i_lo >= i_hi) return;                   // uniform across block
  const int wv = threadIdx.x >> 6, lane = threadIdx.x & 63;
  const int W = Wb + wv;
  const int cnt = i_hi - i_lo;
  if (threadIdx.x < cnt) ib[threadIdx.x] = sb4[i_lo + threadIdx.x];
  __syncthreads();
  const float4 bj = sb4[(W << 6) + lane];
  const float areaJ = (bj.z - bj.x) * (bj.w - bj.y);
  const int n = i_hi - i_lo;
  #pragma unroll 8
  for (int k = 0; k < n; ++k) {
    const float4 bi = ib[k];
    const float areaI = (bi.z - bi.x) * (bi.w - bi.y);
    const float ix1 = fmaxf(bj.x, bi.x), iy1 = fmaxf(bj.y, bi.y);
    const float ix2 = fminf(bj.z, bi.z), iy2 = fminf(bj.w, bi.w);
    const float iw = fmaxf(ix2 - ix1, 0.0f), ih = fmaxf(iy2 - iy1, 0.0f);
    const double inter = (double)iw * (double)ih;
    const double uni = (double)areaJ + (double)areaI - inter + 1e-9;
    const bool pred = inter > 0.3 * uni;
    const u64 bal = __ballot(pred);
    const int i = i_lo + k;
    if (lane == 0) mask[(size_t)i * 144 + W] = bal;
  }
}

// ====== sweep v9: v8 + SCALARIZED greedy chain ==============================
// R11 PMC: 62.5 us, ~9% VALU on its CU, FETCH @ 11.6 GB/s -> serial-chain
// bound. The greedy loop's cand lived in VGPRs (derived from __shfl), so
// each iteration paid v_ffbl + v_readfirstlane + v_readlane x2 (~40-60 cyc).
// v9: one readfirstlane on av at loop entry puts cand in SGPRs -> ctz is
// s_ff1_i32_b64, b is already SGPR (v_readlane index), mask updates are
// s_andn2/s_or. ~3x shorter chain. Values provably uniform -> pure codegen.
__global__ __launch_bounds__(1024) void sweep_out_k(
    const u64* __restrict__ mask, const u64* __restrict__ skeys,
    const float4* __restrict__ sboxes, float* __restrict__ out)
{
  extern __shared__ __align__(16) char sm[];
  u64* subm   = (u64*)sm;                        // 2*4608 u64 = 73,728 B
  u64* supS   = subm + 9216;                     // 2*8 u64    = 128 B
  u64* keptS  = supS + 16;                       // 144 u64    = 1,152 B
  unsigned short* kpl = (unsigned short*)(keptS + 144);  // 9216 u16 = 18,432 B
  int* kcnt  = (int*)(kpl + 9216);               // 4 B   (total 93,444)

  const int tid = threadIdx.x;
  const int lane = tid & 63, wv = tid >> 6;
  if (tid == 0) *kcnt = 0;
  if (tid < 144) keptS[tid] = 0ULL;
  if (tid < 16) supS[tid] = 0ULL;
  // stage sg 0 into buffer 0 (rows 0..511, words 0..7, stride 9)
  if (tid < 512) {
    const int wq = tid & 7, r0 = tid >> 3;
    #pragma unroll
    for (int k = 0; k < 8; ++k) {
      const int i = r0 + (k << 6);
      subm[i * 9 + wq] = mask[(size_t)i * 144 + wq];
    }
  }
  __syncthreads();

  int Kpp = 0, Kp = 0;                           // wave0-only registers

  for (int sg = 0; sg < 18; ++sg) {
    const int buf = sg & 1, nb = buf ^ 1;
    const int wbase = sg << 3;
    const int ibase = wbase << 6;
    if (wv == 0) {
      // ---- delta-pull: rows [Kpp,Kp) x words(sg), no barrier needed ----
      u64 dacc = 0ULL;
      {
        const int wq = lane & 7;
        int j = Kpp + (lane >> 3);
        for (; j + 24 < Kp; j += 32) {
          const u64 a0 = mask[(size_t)kpl[j +  0] * 144 + wbase + wq];
          const u64 a1 = mask[(size_t)kpl[j +  8] * 144 + wbase + wq];
          const u64 a2 = mask[(size_t)kpl[j + 16] * 144 + wbase + wq];
          const u64 a3 = mask[(size_t)kpl[j + 24] * 144 + wbase + wq];
          dacc |= (a0 | a1) | (a2 | a3);
        }
        for (; j < Kp; j += 8)
          dacc |= mask[(size_t)kpl[j] * 144 + wbase + wq];
      }
      dacc |= __shfl_xor(dacc, 8, 64);
      dacc |= __shfl_xor(dacc, 16, 64);
      dacc |= __shfl_xor(dacc, 32, 64);          // lane l: OR for word l&7
      u64 myAlive = (lane < 8) ? ~(supS[(buf << 3) + lane] | dacc) : 0ULL;
      if (lane < 8) supS[(buf << 3) + lane] = 0ULL;  // ready for sg+2 pre-pull
      const u64* sub = subm + buf * 4608;
      // preload all 8 diagonal rowL words (independent ds_reads)
      u64 rowL8[8];
      #pragma unroll
      for (int w = 0; w < 8; ++w)
        rowL8[w] = sub[((w << 6) + lane) * 9 + w];
      int Kcur = Kp;
      #pragma unroll
      for (int w = 0; w < 8; ++w) {
        const u64 av = __shfl(myAlive, w, 64);
        if (av == 0ULL) continue;
        const u64 rowL = rowL8[w];
        // scalarize the uniform candidate mask -> SALU greedy chain
        const unsigned cLo =
            (unsigned)__builtin_amdgcn_readfirstlane((int)(unsigned)av);
        const unsigned cHi =
            (unsigned)__builtin_amdgcn_readfirstlane((int)(unsigned)(av >> 32));
        u64 cand = ((u64)cHi << 32) | cLo;
        u64 keptw = 0ULL;
        while (cand) {
          const int b = (int)__builtin_ctzll(cand);   // s_ff1 (SGPR cand)
          keptw |= 1ULL << b;
          const u64 sup =
              ((u64)(unsigned)__builtin_amdgcn_readlane((int)(rowL >> 32), b)
               << 32) |
              (unsigned)__builtin_amdgcn_readlane((int)rowL, b);
          cand &= ~(sup | (1ULL << b));
        }
        if (lane == 0) keptS[wbase + w] = keptw;
        if (keptw) {
          if ((keptw >> lane) & 1ULL) {
            const int pre =
                __builtin_popcountll(keptw & ((1ULL << lane) - 1ULL));
            kpl[Kcur + pre] = (unsigned short)(ibase + (w << 6) + lane);
          }
          Kcur += __builtin_popcountll(keptw);
          // apply kept rows to later words of this sg (batch 8 per round)
          u64 t = keptw;
          while (t) {
            int bs[8]; int nn = 0;
            #pragma unroll
            for (int s = 0; s < 8; ++s) {
              if (t) { bs[s] = (int)__builtin_ctzll(t); t &= t - 1ULL; nn = s + 1; }
              else bs[s] = 0;
            }
            const int kk = lane >> 3, wq = lane & 7;
            u64 r = (kk < nn) ? sub[((w << 6) + bs[kk]) * 9 + wq] : 0ULL;
            r |= __shfl_down(r, 8, 64);
            r |= __shfl_down(r, 16, 64);
            r |= __shfl_down(r, 32, 64);
            myAlive &= ~r;                       // lanes 0..7 hold the OR
          }
        }
      }
      Kpp = Kp; Kp = Kcur;
      if (lane == 0) *kcnt = Kcur;               // publish once, pre-barrier
    } else if (wv < 12) {                        // pre-pull(sg+1): rows [0,Kh)
      if (sg + 1 < 18) {
        const int Kh = *kcnt;                    // either old or new K: benign
        const int t6 = tid - 64;                 // 0..703
        const int wq = t6 & 7, str = t6 >> 3;    // 88 streams x 8 words
        const int wb2 = (sg + 1) << 3;
        u64 acc = 0ULL;
        int j = str;
        for (; j + 3 * 88 < Kh; j += 4 * 88) {
          const u64 a0 = mask[(size_t)kpl[j + 0 * 88] * 144 + wb2 + wq];
          const u64 a1 = mask[(size_t)kpl[j + 1 * 88] * 144 + wb2 + wq];
          const u64 a2 = mask[(size_t)kpl[j + 2 * 88] * 144 + wb2 + wq];
          const u64 a3 = mask[(size_t)kpl[j + 3 * 88] * 144 + wb2 + wq];
          acc |= (a0 | a1) | (a2 | a3);
        }
        for (; j < Kh; j += 88)
          acc |= mask[(size_t)kpl[j] * 144 + wb2 + wq];
        if (acc) {
          atomicOr((unsigned*)&supS[(nb << 3) + wq], (unsigned)acc);
          atomicOr(((unsigned*)&supS[(nb << 3) + wq]) + 1, (unsigned)(acc >> 32));
        }
      }
    } else if (sg + 1 < 18) {                    // stage(sg+1) into subm[nb]
      const int s = tid - 768;                   // 0..255
      const int wq = s & 7, r0 = s >> 3;         // 32 rows x 16 iters
      const int ib2 = (sg + 1) << 9;
      const int wb2 = (sg + 1) << 3;
      #pragma unroll
      for (int k = 0; k < 16; ++k) {
        const int i = r0 + (k << 5);
        subm[nb * 4608 + i * 9 + wq] = mask[(size_t)(ib2 + i) * 144 + wb2 + wq];
      }
    }
    __syncthreads();                             // orders everything per sg
  }
  for (int i = tid; i < 9216; i += 1024) {
    const u64 key = skeys[i];
    const int orig = 0x7FFFFFFF - (int)(unsigned)(key & 0xFFFFFFFFULL);
    const bool kp = (keptS[i >> 6] >> (i & 63)) & 1ULL;
    float4 ob = sboxes[i];
    if (!kp) { ob.x = 0.f; ob.y = 0.f; ob.z = 0.f; ob.w = 0.f; }
    ((float4*)out)[orig] = ob;
    out[55296 + orig] = kp ? 1.0f : 0.0f;
  }
}

// ================= fallback NMS (small ws) ==================================
__global__ __launch_bounds__(1024) void nms_fallback_k(
    const float* __restrict__ props, float* __restrict__ out)
{
  __shared__ u64 wmax[16];
  __shared__ float4 curBoxS;
  const int tid = threadIdx.x, wid = tid >> 6, lane = tid & 63;
  u64 key[9];
  float4 box[9];
  #pragma unroll
  for (int j = 0; j < 9; ++j) {
    const int r = tid + (j << 10);
    box[j] = ((const float4*)props)[r];
    const float s = out[36864 + ((2 * (r >> 10) + 1) << 10) + (r & 1023)];
    key[j] = ((u64)__float_as_uint(s) << 32) | (unsigned)(0x7FFFFFFF - r);
  }
  unsigned kept = 0;
  for (;;) {
    u64 m = key[0];
    #pragma unroll
    for (int j = 1; j < 9; ++j) m = key[j] > m ? key[j] : m;
    #pragma unroll
    for (int off = 32; off; off >>= 1) {
      const u64 o = __shfl_down(m, off, 64);
      if (o > m) m = o;
    }
    if (lane == 0) wmax[wid] = m;
    __syncthreads();
    u64 K = wmax[0];
    #pragma unroll
    for (int wv2 = 1; wv2 < 16; ++wv2) { const u64 t = wmax[wv2]; if (t > K) K = t; }
    if (K == 0) break;
    #pragma unroll
    for (int j = 0; j < 9; ++j)
      if (key[j] == K) { curBoxS = box[j]; key[j] = 0; kept |= 1u << j; }
    __syncthreads();
    const float4 cb = curBoxS;
    const float areaC = (cb.z - cb.x) * (cb.w - cb.y);
    #pragma unroll
    for (int j = 0; j < 9; ++j) {
      if (key[j]) {
        const float4 b = box[j];
        const float ix1 = fmaxf(b.x, cb.x), iy1 = fmaxf(b.y, cb.y);
        const float ix2 = fminf(b.z, cb.z), iy2 = fminf(b.w, cb.w);
        const float iw = fmaxf(ix2 - ix1, 0.0f), ih = fmaxf(iy2 - iy1, 0.0f);
        const float areaB = (b.z - b.x) * (b.w - b.y);
        const double inter = (double)iw * (double)ih;
        const double uni = (double)areaB + (double)areaC - inter + 1e-9;
        if (inter > 0.3 * uni) key[j] = 0;
      }
    }
    __syncthreads();
  }
  #pragma unroll
  for (int j = 0; j < 9; ++j) {
    const int r = tid + (j << 10);
    const bool kp = (kept >> j) & 1u;
    float4 ob = box[j];
    if (!kp) { ob.x = 0.f; ob.y = 0.f; ob.z = 0.f; ob.w = 0.f; }
    ((float4*)out)[r] = ob;
    out[55296 + r] = kp ? 1.0f : 0.0f;
  }
}

// ============================================================================
extern "C" void kernel_launch(void* const* d_in, const int* in_sizes, int n_in,
                              void* d_out, int out_size, void* d_ws, size_t ws_size,
                              hipStream_t stream)
{
  const float* feat   = (const float*)d_in[0];
  const int*   imgsz  = (const int*)d_in[1];
  const float* conv_w = (const float*)d_in[2];
  const float* conv_b = (const float*)d_in[3];
  const float* cls_w  = (const float*)d_in[4];
  const float* cls_b  = (const float*)d_in[5];
  const float* bbox_w = (const float*)d_in[6];
  const float* bbox_b = (const float*)d_in[7];
  float* out = (float*)d_out;
  char*  ws  = (char*)d_ws;
  float* x      = (float*)(ws + X_B);
  float* bbox   = (float*)(ws + BBOX_B);
  float* props  = (float*)(ws + PROPS_B);
  u64*      keys  = (u64*)(ws + KEYS_B);
  unsigned* rankp = (unsigned*)(ws + RANK_B);
  u64*      skeys = (u64*)(ws + SKEYS_B);
  float4*   sboxs = (float4*)(ws + SBOX_B);
  u64*      maskp = (u64*)(ws + MASK_B);

  if (ws_size >= (size_t)WS_NEED) {
    hipLaunchKernelGGL(conv3x3_mfma_k, dim3(512), dim3(256), 0, stream,
                       feat, conv_w, conv_b, x);
    hipLaunchKernelGGL(head1x1_k, dim3(216), dim3(1024), 0, stream,
                       x, cls_w, cls_b, bbox_w, bbox_b, out, bbox);
    hipLaunchKernelGGL(proposals_k, dim3(36), dim3(256), 0, stream,
                       bbox, imgsz, out, props, keys, rankp);
    hipLaunchKernelGGL(rank_k, dim3(576), dim3(256), 0, stream, keys, rankp);
    hipLaunchKernelGGL(scatter_k, dim3(36), dim3(256), 0, stream,
                       keys, rankp, props, skeys, sboxs);
    hipLaunchKernelGGL(mask_k, dim3(144, 36), dim3(256), 0, stream,
                       sboxs, maskp);
    hipLaunchKernelGGL(sweep_out_k, dim3(1), dim3(1024), 93444, stream,
                       maskp, skeys, sboxs, out);
  } else {
    hipLaunchKernelGGL(conv3x3_relu_fb_k, dim3(512), dim3(256), 0, stream,
                       feat, conv_w, conv_b, x);
    hipLaunchKernelGGL(head1x1_k, dim3(216), dim3(1024), 0, stream,
                       x, cls_w, cls_b, bbox_w, bbox_b, out, bbox);
    hipLaunchKernelGGL(proposals_k, dim3(36), dim3(256), 0, stream,
                       bbox, imgsz, out, props, keys, rankp);
    hipLaunchKernelGGL(nms_fallback_k, dim3(1), dim3(1024), 0, stream,
                       props, out);
  }
}